// Round 2
// baseline (593.440 us; speedup 1.0000x reference)
//
#include <hip/hip_runtime.h>
#include <math.h>

#define NB 4
#define NC 256
#define NHW 4096
#define NC8 32
#define NC2 128

typedef unsigned short u16;
typedef __attribute__((ext_vector_type(8))) short s8v;   // 8 x bf16 (MFMA A/B frag)
typedef __attribute__((ext_vector_type(4))) float f4v;   // 4 x f32  (MFMA C/D frag)

__device__ __forceinline__ u16 f2bf(float x) {
    unsigned int u = __builtin_bit_cast(unsigned int, x);
    u += 0x7FFFu + ((u >> 16) & 1u);          // RNE
    return (u16)(u >> 16);
}
__device__ __forceinline__ float bf2f(u16 h) {
    unsigned int u = ((unsigned int)h) << 16;
    return __builtin_bit_cast(float, u);
}

#define MFMA16(a, b, c) __builtin_amdgcn_mfma_f32_16x16x32_bf16((a), (b), (c), 0, 0, 0)

// ---------------------------------------------------------------------------
// K1: conv3x3 partials. grid (16 co-groups of 4, 4 ci-chunks of 64, B).
// Each block stages one input plane at a time (dbuf, stride-65 pad) and
// computes 4 output channels -> partial sums (no bias/bn yet).
// ---------------------------------------------------------------------------
__global__ __launch_bounds__(256) void k_conv_qk(
    const float* __restrict__ x,
    const float* __restrict__ qw, const float* __restrict__ kw,
    float* __restrict__ part)
{
    __shared__ float plane[2][64 * 65];
    const int cog = blockIdx.x;          // 0..15 -> co = cog*4..+3 (0..63)
    const int cic = blockIdx.y;          // 0..3  -> ci chunk of 64
    const int b   = blockIdx.z;
    const int t   = threadIdx.x;
    const int co0 = cog * 4;
    const bool isq = co0 < NC8;
    const int oc0 = isq ? co0 : co0 - NC8;
    const float* wsel = isq ? qw : kw;   // [32][256][9]
    const int ci0 = cic * 64;
    const int r  = t >> 2;               // output row 0..63
    const int c0 = (t & 3) * 16;         // output col strip
    float acc[4][16];
#pragma unroll
    for (int j = 0; j < 4; ++j)
#pragma unroll
        for (int q = 0; q < 16; ++q) acc[j][q] = 0.f;

    const float* xb = x + (size_t)b * NC * NHW;
    float4 pf[4];
    {
        const float4* src = (const float4*)(xb + (size_t)ci0 * NHW);
#pragma unroll
        for (int u = 0; u < 4; ++u) pf[u] = src[t + 256 * u];
    }
    for (int ci = ci0; ci < ci0 + 64; ++ci) {
        const int cur = ci & 1;
#pragma unroll
        for (int u = 0; u < 4; ++u) {
            int g  = (t + 256 * u) << 2;
            int rr = g >> 6, cc = g & 63;
            float* p = &plane[cur][rr * 65 + cc];
            p[0] = pf[u].x; p[1] = pf[u].y; p[2] = pf[u].z; p[3] = pf[u].w;
        }
        __syncthreads();
        if (ci + 1 < ci0 + 64) {
            const float4* src = (const float4*)(xb + (size_t)(ci + 1) * NHW);
#pragma unroll
            for (int u = 0; u < 4; ++u) pf[u] = src[t + 256 * u];
        }
        float w9[4][9];
#pragma unroll
        for (int j = 0; j < 4; ++j)
#pragma unroll
            for (int u = 0; u < 9; ++u)
                w9[j][u] = wsel[((size_t)(oc0 + j) * NC + ci) * 9 + u];
#pragma unroll
        for (int dy = 0; dy < 3; ++dy) {
            int rr = r + dy - 1;
            if (rr >= 0 && rr <= 63) {
                const float* row = &plane[cur][rr * 65];
                float tv[18];
#pragma unroll
                for (int jj = 0; jj < 18; ++jj) {
                    int cc = c0 + jj - 1;
                    tv[jj] = (cc >= 0 && cc < 64) ? row[cc] : 0.f;
                }
#pragma unroll
                for (int j = 0; j < 4; ++j) {
                    float wa = w9[j][dy * 3 + 0], wb = w9[j][dy * 3 + 1], wc = w9[j][dy * 3 + 2];
#pragma unroll
                    for (int q = 0; q < 16; ++q)
                        acc[j][q] += wa * tv[q] + wb * tv[q + 1] + wc * tv[q + 2];
                }
            }
        }
        __syncthreads();
    }
    float* pp = part + (((size_t)(cic * 4 + b) * 64 + co0) * NHW) + r * 64 + c0;
#pragma unroll
    for (int j = 0; j < 4; ++j)
#pragma unroll
        for (int q4 = 0; q4 < 4; ++q4) {
            float4 o;
            o.x = acc[j][q4 * 4 + 0]; o.y = acc[j][q4 * 4 + 1];
            o.z = acc[j][q4 * 4 + 2]; o.w = acc[j][q4 * 4 + 3];
            *(float4*)(pp + (size_t)j * NHW + q4 * 4) = o;
        }
}

// ---------------------------------------------------------------------------
// K1b: sum 4 ci-chunk partials + bias + bn + relu -> q/k bf16 hi/lo in
// [b][pixel][32ch] layout (MFMA B-frag friendly). grid (64 px-chunks, B).
// ---------------------------------------------------------------------------
__global__ __launch_bounds__(256) void k_qk_finish(
    const float* __restrict__ part,
    const float* __restrict__ qb, const float* __restrict__ qbs, const float* __restrict__ qbb,
    const float* __restrict__ qbm, const float* __restrict__ qbv,
    const float* __restrict__ kb, const float* __restrict__ kbs, const float* __restrict__ kbb,
    const float* __restrict__ kbm, const float* __restrict__ kbv,
    u16* __restrict__ qh, u16* __restrict__ ql,
    u16* __restrict__ kh, u16* __restrict__ kl)
{
    const int t = threadIdx.x;
    const int b = blockIdx.y;
    const int n = blockIdx.x * 64 + (t & 63);
    const int coq = t >> 6;              // 0,1 -> q halves; 2,3 -> k halves
    const int cb2 = coq * 16;
    float s[16];
#pragma unroll
    for (int j = 0; j < 16; ++j) s[j] = 0.f;
#pragma unroll
    for (int cic = 0; cic < 4; ++cic)
#pragma unroll
        for (int j = 0; j < 16; ++j)
            s[j] += part[(((size_t)(cic * 4 + b)) * 64 + cb2 + j) * NHW + n];
    const bool isq = coq < 2;
    u16 hi[16], lo[16];
#pragma unroll
    for (int j = 0; j < 16; ++j) {
        int oc = (coq & 1) * 16 + j;
        float cbv = isq ? qb[oc]  : kb[oc];
        float sv  = isq ? qbs[oc] : kbs[oc];
        float bbv = isq ? qbb[oc] : kbb[oc];
        float mv  = isq ? qbm[oc] : kbm[oc];
        float vv  = isq ? qbv[oc] : kbv[oc];
        float inv = rsqrtf(vv + 1e-5f);
        float scale = inv * sv;
        float shift = (cbv - mv) * scale + bbv;
        float y = fmaxf(s[j] * scale + shift, 0.f);
        hi[j] = f2bf(y);
        lo[j] = f2bf(y - bf2f(hi[j]));
    }
    u16* dh = isq ? qh : kh;
    u16* dl = isq ? ql : kl;
    size_t base = ((size_t)b * NHW + n) * 32 + (coq & 1) * 16;
    uint4 ph0, ph1, pl0, pl1;
    ph0.x = (unsigned)hi[0]  | ((unsigned)hi[1]  << 16);
    ph0.y = (unsigned)hi[2]  | ((unsigned)hi[3]  << 16);
    ph0.z = (unsigned)hi[4]  | ((unsigned)hi[5]  << 16);
    ph0.w = (unsigned)hi[6]  | ((unsigned)hi[7]  << 16);
    ph1.x = (unsigned)hi[8]  | ((unsigned)hi[9]  << 16);
    ph1.y = (unsigned)hi[10] | ((unsigned)hi[11] << 16);
    ph1.z = (unsigned)hi[12] | ((unsigned)hi[13] << 16);
    ph1.w = (unsigned)hi[14] | ((unsigned)hi[15] << 16);
    pl0.x = (unsigned)lo[0]  | ((unsigned)lo[1]  << 16);
    pl0.y = (unsigned)lo[2]  | ((unsigned)lo[3]  << 16);
    pl0.z = (unsigned)lo[4]  | ((unsigned)lo[5]  << 16);
    pl0.w = (unsigned)lo[6]  | ((unsigned)lo[7]  << 16);
    pl1.x = (unsigned)lo[8]  | ((unsigned)lo[9]  << 16);
    pl1.y = (unsigned)lo[10] | ((unsigned)lo[11] << 16);
    pl1.z = (unsigned)lo[12] | ((unsigned)lo[13] << 16);
    pl1.w = (unsigned)lo[14] | ((unsigned)lo[15] << 16);
    *(uint4*)&dh[base]     = ph0;
    *(uint4*)&dh[base + 8] = ph1;
    *(uint4*)&dl[base]     = pl0;
    *(uint4*)&dl[base + 8] = pl1;
}

// ---------------------------------------------------------------------------
// K2: dual 1x1 conv: v2T[b,n,o] fp32 (for reduce) + v bf16 hi/lo [b][o][n].
// ---------------------------------------------------------------------------
__global__ __launch_bounds__(256) void k_gemm_vv2(
    const float* __restrict__ x,
    const float* __restrict__ vw, const float* __restrict__ vb,
    const float* __restrict__ sw, const float* __restrict__ sb,
    float* __restrict__ v2T, u16* __restrict__ vhi, u16* __restrict__ vlo)
{
    __shared__ float Ax[16 * 68];
    __shared__ float Bw1[16 * 68];
    __shared__ float Bw2[16 * 68];
    const int t  = threadIdx.x;
    const int n0 = blockIdx.x * 64;
    const int o0 = blockIdx.y * 64;
    const int b  = blockIdx.z;
    const int ni = t & 15, oi = t >> 4;
    float a1[4][4], a2[4][4];
#pragma unroll
    for (int i = 0; i < 4; ++i)
#pragma unroll
        for (int j = 0; j < 4; ++j) { a1[i][j] = 0.f; a2[i][j] = 0.f; }

    const int sk  = t >> 4;
    const int sf  = t & 15;
    const int so  = t & 63;
    const int skq = t >> 6;
    const float* xb = x + ((size_t)b * NC) * NHW + n0;

    float4 ax = *(const float4*)(xb + (size_t)sk * NHW + sf * 4);
    float4 f1 = *(const float4*)(vw + (size_t)(o0 + so) * NC + skq * 4);
    float4 f2 = *(const float4*)(sw + (size_t)(o0 + so) * NC + skq * 4);

    for (int c0 = 0; c0 < NC; c0 += 16) {
        *(float4*)&Ax[sk * 68 + sf * 4] = ax;
        Bw1[(skq * 4 + 0) * 68 + so] = f1.x;
        Bw1[(skq * 4 + 1) * 68 + so] = f1.y;
        Bw1[(skq * 4 + 2) * 68 + so] = f1.z;
        Bw1[(skq * 4 + 3) * 68 + so] = f1.w;
        Bw2[(skq * 4 + 0) * 68 + so] = f2.x;
        Bw2[(skq * 4 + 1) * 68 + so] = f2.y;
        Bw2[(skq * 4 + 2) * 68 + so] = f2.z;
        Bw2[(skq * 4 + 3) * 68 + so] = f2.w;
        __syncthreads();
        if (c0 + 16 < NC) {
            ax = *(const float4*)(xb + (size_t)(c0 + 16 + sk) * NHW + sf * 4);
            f1 = *(const float4*)(vw + (size_t)(o0 + so) * NC + c0 + 16 + skq * 4);
            f2 = *(const float4*)(sw + (size_t)(o0 + so) * NC + c0 + 16 + skq * 4);
        }
#pragma unroll
        for (int k = 0; k < 16; ++k) {
            float4 af = *(const float4*)&Ax[k * 68 + ni * 4];
            float4 g1 = *(const float4*)&Bw1[k * 68 + oi * 4];
            float4 g2 = *(const float4*)&Bw2[k * 68 + oi * 4];
            const float* ap = (const float*)&af;
            const float* p1 = (const float*)&g1;
            const float* p2 = (const float*)&g2;
#pragma unroll
            for (int i = 0; i < 4; ++i)
#pragma unroll
                for (int j = 0; j < 4; ++j) {
                    a1[i][j] += ap[i] * p1[j];
                    a2[i][j] += ap[i] * p2[j];
                }
        }
        __syncthreads();
    }
    float vb4[4], sb4[4];
#pragma unroll
    for (int j = 0; j < 4; ++j) { vb4[j] = vb[o0 + oi * 4 + j]; sb4[j] = sb[o0 + oi * 4 + j]; }
#pragma unroll
    for (int i = 0; i < 4; ++i) {
        size_t idx = ((size_t)b * NHW + n0 + ni * 4 + i) * NC + o0 + oi * 4;
        float4 o2v;
        o2v.x = a2[i][0] + sb4[0]; o2v.y = a2[i][1] + sb4[1];
        o2v.z = a2[i][2] + sb4[2]; o2v.w = a2[i][3] + sb4[3];
        *(float4*)&v2T[idx] = o2v;
    }
#pragma unroll
    for (int j = 0; j < 4; ++j) {
        u16 h[4], l[4];
#pragma unroll
        for (int i = 0; i < 4; ++i) {
            float y = a1[i][j] + vb4[j];
            h[i] = f2bf(y);
            l[i] = f2bf(y - bf2f(h[i]));
        }
        size_t vi = ((size_t)b * NC + o0 + oi * 4 + j) * NHW + n0 + ni * 4;
        uint2 uh, ul;
        uh.x = (unsigned)h[0] | ((unsigned)h[1] << 16);
        uh.y = (unsigned)h[2] | ((unsigned)h[3] << 16);
        ul.x = (unsigned)l[0] | ((unsigned)l[1] << 16);
        ul.y = (unsigned)l[2] | ((unsigned)l[3] << 16);
        *(uint2*)&vhi[vi] = uh;
        *(uint2*)&vlo[vi] = ul;
    }
}

// ---------------------------------------------------------------------------
// K3: channel max/mean of v2T rows -> smo[b,{max,mean},n]
// ---------------------------------------------------------------------------
__global__ __launch_bounds__(256) void k_reduce_v2(const float* __restrict__ v2T,
                                                   float* __restrict__ smo)
{
    const int t = threadIdx.x;
    const int lane = t & 63, wv = t >> 6;
    const int row = blockIdx.x * 4 + wv;
    float4 f = ((const float4*)(v2T + (size_t)row * NC))[lane];
    float mx = fmaxf(fmaxf(f.x, f.y), fmaxf(f.z, f.w));
    float sm = f.x + f.y + f.z + f.w;
#pragma unroll
    for (int off = 32; off; off >>= 1) {
        mx = fmaxf(mx, __shfl_down(mx, off));
        sm += __shfl_down(sm, off);
    }
    if (lane == 0) {
        int b = row >> 12, n = row & 4095;
        smo[((size_t)b * 2 + 0) * NHW + n] = mx;
        smo[((size_t)b * 2 + 1) * NHW + n] = sm * (1.f / NC);
    }
}

// ---------------------------------------------------------------------------
// K4: conv3x3(2ch->1) + bn + row softmax -> Amat[b,w,k]
// ---------------------------------------------------------------------------
__global__ __launch_bounds__(256) void k_spatial(
    const float* __restrict__ smo, const float* __restrict__ scw,
    const float* __restrict__ scb, const float* __restrict__ sbs,
    const float* __restrict__ sbb2, const float* __restrict__ sbm,
    const float* __restrict__ sbv, float* __restrict__ Amat)
{
    __shared__ float ch[2][64 * 68];
    __shared__ float lg[64 * 68];
    const int t = threadIdx.x;
    const int b = blockIdx.x;
#pragma unroll
    for (int u = 0; u < 8; ++u) {
        int g  = t + 256 * u;
        int c  = g >> 10, gi = g & 1023;
        int row = gi >> 4, col4 = (gi & 15) * 4;
        float4 f = ((const float4*)(smo + ((size_t)b * 2 + c) * NHW))[gi];
        *(float4*)&ch[c][row * 68 + col4] = f;
    }
    __syncthreads();
    float w9[2][9];
#pragma unroll
    for (int ic = 0; ic < 2; ++ic)
#pragma unroll
        for (int j = 0; j < 9; ++j) w9[ic][j] = scw[ic * 9 + j];
    float A0, Bsh;
    {
        float inv = rsqrtf(sbv[0] + 1e-5f);
        A0  = inv * sbs[0];
        Bsh = (scb[0] - sbm[0]) * A0 + sbb2[0];
    }
#pragma unroll
    for (int u = 0; u < 16; ++u) {
        int px = t + 256 * u;
        int h = px >> 6, w = px & 63;
        float acc = 0.f;
#pragma unroll
        for (int ic = 0; ic < 2; ++ic)
#pragma unroll
            for (int dy = 0; dy < 3; ++dy) {
                int rr = h + dy - 1;
                if (rr < 0 || rr > 63) continue;
#pragma unroll
                for (int dx = 0; dx < 3; ++dx) {
                    int cc = w + dx - 1;
                    if (cc < 0 || cc > 63) continue;
                    acc += w9[ic][dy * 3 + dx] * ch[ic][rr * 68 + cc];
                }
            }
        lg[h * 68 + w] = acc * A0 + Bsh;
    }
    __syncthreads();
    if (t < 64) {
        float M = -INFINITY;
        for (int k2 = 0; k2 < 64; ++k2) M = fmaxf(M, lg[t * 68 + k2]);
        float L = 0.f;
        for (int k2 = 0; k2 < 64; ++k2) L += __expf(lg[t * 68 + k2] - M);
        float rli = 1.f / L;
        for (int k2 = 0; k2 < 64; ++k2)
            Amat[(size_t)b * NHW + t * 64 + k2] = __expf(lg[t * 68 + k2] - M) * rli;
    }
}

// ---------------------------------------------------------------------------
// K5: per-(b,c) spatial mean & max of x
// ---------------------------------------------------------------------------
__global__ __launch_bounds__(256) void k_xstats(const float* __restrict__ x,
                                                float* __restrict__ smean,
                                                float* __restrict__ smax)
{
    const int t = threadIdx.x;
    const int c = blockIdx.x, b = blockIdx.y;
    const float* row = x + ((size_t)b * NC + c) * NHW;
    float s = 0.f, m = -INFINITY;
#pragma unroll
    for (int u = 0; u < 4; ++u) {
        float4 f = ((const float4*)row)[t + 256 * u];
        s += f.x + f.y + f.z + f.w;
        m = fmaxf(m, fmaxf(fmaxf(f.x, f.y), fmaxf(f.z, f.w)));
    }
    __shared__ float red[8];
    const int lane = t & 63, wv = t >> 6;
#pragma unroll
    for (int off = 32; off; off >>= 1) {
        s += __shfl_down(s, off);
        m = fmaxf(m, __shfl_down(m, off));
    }
    if (lane == 0) { red[wv] = s; red[4 + wv] = m; }
    __syncthreads();
    if (t == 0) {
        float S = red[0] + red[1] + red[2] + red[3];
        float M = fmaxf(fmaxf(red[4], red[5]), fmaxf(red[6], red[7]));
        smean[b * NC + c] = S * (1.f / NHW);
        smax[b * NC + c]  = M;
    }
}

// ---------------------------------------------------------------------------
// K6: channel gate
// ---------------------------------------------------------------------------
__global__ __launch_bounds__(256) void k_gate(
    const float* __restrict__ smean, const float* __restrict__ smax,
    const float* __restrict__ w1, const float* __restrict__ b1,
    const float* __restrict__ w2, const float* __restrict__ b2,
    float* __restrict__ gate)
{
    __shared__ float smL[256], sxL[256], hL[256];
    const int t = threadIdx.x;
    const int b = blockIdx.x;
    smL[t] = smean[b * NC + t];
    sxL[t] = smax[b * NC + t];
    __syncthreads();
    {
        const int j = t & 127;
        const float* in = (t < 128) ? smL : sxL;
        const float* wr = w1 + (size_t)j * NC;
        float acc = b1[j];
        for (int c = 0; c < NC; c += 4) {
            float4 f = *(const float4*)(wr + c);
            acc += f.x * in[c] + f.y * in[c + 1] + f.z * in[c + 2] + f.w * in[c + 3];
        }
        hL[t] = fmaxf(acc, 0.f);
    }
    __syncthreads();
    {
        const float* wr = w2 + (size_t)t * NC2;
        float acc = 2.f * b2[t];
        for (int j = 0; j < NC2; j += 4) {
            float4 f = *(const float4*)(wr + j);
            acc += f.x * (hL[j]     + hL[128 + j])
                 + f.y * (hL[j + 1] + hL[129 + j])
                 + f.z * (hL[j + 2] + hL[130 + j])
                 + f.w * (hL[j + 3] + hL[131 + j]);
        }
        gate[b * NC + t] = 1.f / (1.f + __expf(-acc));
    }
}

// ---------------------------------------------------------------------------
// K7: softmax row stats via bf16-split MFMA (swapped: S^T = K^T Q).
// 64-thread blocks, 16 n-rows each. grid (256, B).
// ---------------------------------------------------------------------------
__global__ __launch_bounds__(64) void k_softstats(
    const u16* __restrict__ qh, const u16* __restrict__ ql,
    const u16* __restrict__ kh, const u16* __restrict__ kl,
    float* __restrict__ mx, float* __restrict__ rl)
{
    const int t  = threadIdx.x;
    const int li = t & 15, g = t >> 4;
    const int n0 = blockIdx.x * 16;
    const int b  = blockIdx.y;
    const size_t qoff = ((size_t)b * NHW + n0 + li) * 32 + g * 8;
    const s8v qfh = *(const s8v*)&qh[qoff];
    const s8v qfl = *(const s8v*)&ql[qoff];
    const size_t kb0 = ((size_t)b * NHW + li) * 32 + g * 8;   // + m*32
    s8v ka0 = *(const s8v*)&kh[kb0];
    s8v ka1 = *(const s8v*)&kh[kb0 + 512];
    s8v la0 = *(const s8v*)&kl[kb0];
    s8v la1 = *(const s8v*)&kl[kb0 + 512];
    float mrun = -INFINITY, lrun = 0.f;
    for (int it = 0; it < 128; ++it) {
        f4v c0 = {0.f, 0.f, 0.f, 0.f}, c1 = {0.f, 0.f, 0.f, 0.f};
        c0 = MFMA16(ka0, qfh, c0); c0 = MFMA16(ka0, qfl, c0); c0 = MFMA16(la0, qfh, c0);
        c1 = MFMA16(ka1, qfh, c1); c1 = MFMA16(ka1, qfl, c1); c1 = MFMA16(la1, qfh, c1);
        if (it + 1 < 128) {
            size_t o = kb0 + (size_t)(it + 1) * 1024;
            ka0 = *(const s8v*)&kh[o];
            ka1 = *(const s8v*)&kh[o + 512];
            la0 = *(const s8v*)&kl[o];
            la1 = *(const s8v*)&kl[o + 512];
        }
        float tmax = fmaxf(fmaxf(fmaxf(c0[0], c0[1]), fmaxf(c0[2], c0[3])),
                           fmaxf(fmaxf(c1[0], c1[1]), fmaxf(c1[2], c1[3])));
        tmax = fmaxf(tmax, __shfl_xor(tmax, 16));
        tmax = fmaxf(tmax, __shfl_xor(tmax, 32));
        float nm = fmaxf(mrun, tmax);
        float ls = 0.f;
#pragma unroll
        for (int r = 0; r < 4; ++r) ls += __expf(c0[r] - nm);
#pragma unroll
        for (int r = 0; r < 4; ++r) ls += __expf(c1[r] - nm);
        ls += __shfl_xor(ls, 16);
        ls += __shfl_xor(ls, 32);
        lrun = lrun * __expf(mrun - nm) + ls;
        mrun = nm;
    }
    if (g == 0) {
        mx[(size_t)b * NHW + n0 + li] = mrun;
        rl[(size_t)b * NHW + n0 + li] = 1.f / lrun;
    }
}

// ---------------------------------------------------------------------------
// K8: flash pass B, bf16-split MFMA. Block = 64n x 256c, 4 waves (16n each).
// Per it (32 m): stage V tile (hi/lo) to LDS; S^T = K^T Q per wave (MFMA);
// p=exp(S-mx)*rl split to bf16 hi/lo, laid out via per-wave LDS scratch into
// A-frags; PV accumulates 16 N-tiles x 3 MFMA. XCD-swizzled blockIdx.
// ---------------------------------------------------------------------------
__global__ __launch_bounds__(256, 2) void k_flash(
    const u16* __restrict__ qh, const u16* __restrict__ ql,
    const u16* __restrict__ kh, const u16* __restrict__ kl,
    const u16* __restrict__ vhi, const u16* __restrict__ vlo,
    const float* __restrict__ mx, const float* __restrict__ rl,
    float* __restrict__ w0, float* __restrict__ w1)
{
    __shared__ __align__(16) u16 SvH[256 * 40];
    __shared__ __align__(16) u16 SvL[256 * 40];
    __shared__ __align__(16) u16 Sp[4][2][16 * 40];
    const int t = threadIdx.x;
    // XCD swizzle: 512 blocks, 64 consecutive virtual blocks (one (mh,b)) per XCD
    const int bid = blockIdx.x;
    const int v   = (bid & 7) * 64 + (bid >> 3);
    const int n0  = (v & 63) * 64;
    const int mh  = (v >> 6) & 1;
    const int b   = v >> 7;
    const int mbase = mh * 2048;
    const int li = t & 15, g = (t >> 4) & 3, wv = t >> 6;
    const int sc = t >> 2, sp = t & 3;
    // persistent Q B-frags (wave's 16 n-rows)
    const size_t qoff = ((size_t)b * NHW + n0 + wv * 16 + li) * 32 + g * 8;
    const s8v qfh = *(const s8v*)&qh[qoff];
    const s8v qfl = *(const s8v*)&ql[qoff];
    const float mxv = mx[(size_t)b * NHW + n0 + wv * 16 + li];
    const float rlv = rl[(size_t)b * NHW + n0 + wv * 16 + li];
    f4v acc[16];
#pragma unroll
    for (int nt = 0; nt < 16; ++nt) { f4v z = {0.f, 0.f, 0.f, 0.f}; acc[nt] = z; }
    // V staging prefetch (it=0)
    size_t vr[4];
#pragma unroll
    for (int u = 0; u < 4; ++u)
        vr[u] = ((size_t)b * NC + sc + u * 64) * NHW + mbase;
    s8v pvh[4], pvl[4];
#pragma unroll
    for (int u = 0; u < 4; ++u) {
        pvh[u] = *(const s8v*)&vhi[vr[u] + sp * 8];
        pvl[u] = *(const s8v*)&vlo[vr[u] + sp * 8];
    }
    // K A-frag prefetch (it=0)
    const size_t kb0 = ((size_t)b * NHW + mbase + li) * 32 + g * 8;
    s8v ka0 = *(const s8v*)&kh[kb0];
    s8v ka1 = *(const s8v*)&kh[kb0 + 512];
    s8v la0 = *(const s8v*)&kl[kb0];
    s8v la1 = *(const s8v*)&kl[kb0 + 512];

    for (int it = 0; it < 64; ++it) {
        __syncthreads();                    // previous tile's reads done
#pragma unroll
        for (int u = 0; u < 4; ++u) {
            *(s8v*)&SvH[(sc + u * 64) * 40 + sp * 8] = pvh[u];
            *(s8v*)&SvL[(sc + u * 64) * 40 + sp * 8] = pvl[u];
        }
        __syncthreads();                    // Sv tile ready
        if (it + 1 < 64) {
#pragma unroll
            for (int u = 0; u < 4; ++u) {
                pvh[u] = *(const s8v*)&vhi[vr[u] + (size_t)(it + 1) * 32 + sp * 8];
                pvl[u] = *(const s8v*)&vlo[vr[u] + (size_t)(it + 1) * 32 + sp * 8];
            }
        }
        // S^T = K^T Q for this wave's 16 n x 32 m
        f4v c0 = {0.f, 0.f, 0.f, 0.f}, c1 = {0.f, 0.f, 0.f, 0.f};
        c0 = MFMA16(ka0, qfh, c0); c0 = MFMA16(ka0, qfl, c0); c0 = MFMA16(la0, qfh, c0);
        c1 = MFMA16(ka1, qfh, c1); c1 = MFMA16(ka1, qfl, c1); c1 = MFMA16(la1, qfh, c1);
        if (it + 1 < 64) {
            size_t o = kb0 + (size_t)(it + 1) * 1024;
            ka0 = *(const s8v*)&kh[o];
            ka1 = *(const s8v*)&kh[o + 512];
            la0 = *(const s8v*)&kl[o];
            la1 = *(const s8v*)&kl[o + 512];
        }
        // P = exp(S - mx) * rl, split hi/lo, write to wave-private scratch
        u16 h0[4], l0[4], h1[4], l1[4];
#pragma unroll
        for (int r = 0; r < 4; ++r) {
            float p = __expf(c0[r] - mxv) * rlv;
            h0[r] = f2bf(p); l0[r] = f2bf(p - bf2f(h0[r]));
            float q = __expf(c1[r] - mxv) * rlv;
            h1[r] = f2bf(q); l1[r] = f2bf(q - bf2f(h1[r]));
        }
        uint2 uw;
        uw.x = (unsigned)h0[0] | ((unsigned)h0[1] << 16);
        uw.y = (unsigned)h0[2] | ((unsigned)h0[3] << 16);
        *(uint2*)&Sp[wv][0][li * 40 + g * 4] = uw;               // mt0 hi
        uw.x = (unsigned)h1[0] | ((unsigned)h1[1] << 16);
        uw.y = (unsigned)h1[2] | ((unsigned)h1[3] << 16);
        *(uint2*)&Sp[wv][0][li * 40 + 16 + g * 4] = uw;          // mt1 hi
        uw.x = (unsigned)l0[0] | ((unsigned)l0[1] << 16);
        uw.y = (unsigned)l0[2] | ((unsigned)l0[3] << 16);
        *(uint2*)&Sp[wv][1][li * 40 + g * 4] = uw;               // mt0 lo
        uw.x = (unsigned)l1[0] | ((unsigned)l1[1] << 16);
        uw.y = (unsigned)l1[2] | ((unsigned)l1[3] << 16);
        *(uint2*)&Sp[wv][1][li * 40 + 16 + g * 4] = uw;          // mt1 lo
        // A-frags (wave-local LDS round trip; compiler inserts lgkmcnt)
        s8v ah = *(const s8v*)&Sp[wv][0][li * 40 + g * 8];
        s8v al = *(const s8v*)&Sp[wv][1][li * 40 + g * 8];
        // PV: 16 N-tiles
#pragma unroll
        for (int nt = 0; nt < 16; ++nt) {
            s8v vh = *(const s8v*)&SvH[(nt * 16 + li) * 40 + g * 8];
            s8v vl = *(const s8v*)&SvL[(nt * 16 + li) * 40 + g * 8];
            acc[nt] = MFMA16(ah, vh, acc[nt]);
            acc[nt] = MFMA16(ah, vl, acc[nt]);
            acc[nt] = MFMA16(al, vh, acc[nt]);
        }
    }
    float* wout = (mh == 0) ? w0 : w1;
#pragma unroll
    for (int nt = 0; nt < 16; ++nt)
#pragma unroll
        for (int r = 0; r < 4; ++r)
            wout[((size_t)b * NHW + n0 + wv * 16 + g * 4 + r) * NC + nt * 16 + li] = acc[nt][r];
}

// ---------------------------------------------------------------------------
// K9: out = gamma*(w0+w1) + x*(1+gate) + spatial term
// ---------------------------------------------------------------------------
__global__ __launch_bounds__(256) void k_final(
    const float* __restrict__ x, const float* __restrict__ w0,
    const float* __restrict__ w1, const float* __restrict__ gate,
    const float* __restrict__ Amat, const float* __restrict__ gamma,
    float* __restrict__ out)
{
    const int t = threadIdx.x;
    const int h = blockIdx.x, b = blockIdx.y;
    const int kx = t & 63, wv = t >> 6;
    const float g0 = gamma[0];
    float Areg[64];
#pragma unroll
    for (int w = 0; w < 64; ++w)
        Areg[w] = Amat[(size_t)b * NHW + w * 64 + kx];
    for (int cc = 0; cc < 64; ++cc) {
        const int c = cc * 4 + wv;
        const size_t xidx = ((size_t)(b * NC + c)) * NHW + h * 64 + kx;
        const float xv = x[xidx];
        float spat = 0.f;
#pragma unroll
        for (int w = 0; w < 64; ++w)
            spat += __shfl(xv, w, 64) * Areg[w];
        const size_t widx = ((size_t)b * NHW + h * 64 + kx) * NC + c;
        const float wsum = w0[widx] + w1[widx];
        const float gt = gate[b * NC + c];
        out[xidx] = g0 * wsum + xv * (1.f + gt) + spat;
    }
}

// ---------------------------------------------------------------------------
extern "C" void kernel_launch(void* const* d_in, const int* in_sizes, int n_in,
                              void* d_out, int out_size, void* d_ws, size_t ws_size,
                              hipStream_t stream)
{
    const float* x    = (const float*)d_in[0];
    const float* qw   = (const float*)d_in[1];
    const float* qb   = (const float*)d_in[2];
    const float* qbs  = (const float*)d_in[3];
    const float* qbb  = (const float*)d_in[4];
    const float* qbm  = (const float*)d_in[5];
    const float* qbv  = (const float*)d_in[6];
    const float* kw   = (const float*)d_in[7];
    const float* kb   = (const float*)d_in[8];
    const float* kbs  = (const float*)d_in[9];
    const float* kbb  = (const float*)d_in[10];
    const float* kbm  = (const float*)d_in[11];
    const float* kbv  = (const float*)d_in[12];
    const float* vw   = (const float*)d_in[13];
    const float* vb   = (const float*)d_in[14];
    const float* gm   = (const float*)d_in[15];
    const float* cw1  = (const float*)d_in[16];
    const float* cb1  = (const float*)d_in[17];
    const float* cw2  = (const float*)d_in[18];
    const float* cb2  = (const float*)d_in[19];
    const float* svw  = (const float*)d_in[20];
    const float* svb  = (const float*)d_in[21];
    const float* scw  = (const float*)d_in[22];
    const float* scb  = (const float*)d_in[23];
    const float* sbs  = (const float*)d_in[24];
    const float* sbb  = (const float*)d_in[25];
    const float* sbm  = (const float*)d_in[26];
    const float* sbv  = (const float*)d_in[27];

    float* ws    = (float*)d_ws;
    float* part  = ws;                      // 4,194,304 f  (reused as w0)
    float* w0    = ws;
    float* v2T   = ws + 4194304;            // 4,194,304 f  (reused as w1)
    float* w1    = ws + 4194304;
    u16*   vhi   = (u16*)(ws + 8388608);    // 4,194,304 u16
    u16*   vlo   = (u16*)(ws + 10485760);
    u16*   qhB   = (u16*)(ws + 12582912);   //   524,288 u16
    u16*   qlB   = (u16*)(ws + 12845056);
    u16*   khB   = (u16*)(ws + 13107200);
    u16*   klB   = (u16*)(ws + 13369344);
    float* mxp   = ws + 13631488;
    float* rlp   = ws + 13647872;
    float* smean = ws + 13664256;
    float* smax  = ws + 13665280;
    float* gate  = ws + 13666304;
    float* smo   = ws + 13667328;
    float* Amat  = ws + 13700096;
    // total 13,716,480 floats ~= 54.9 MB

    k_conv_qk  <<<dim3(16, 4, NB), 256, 0, stream>>>(x, qw, kw, part);
    k_qk_finish<<<dim3(64, NB),    256, 0, stream>>>(part, qb, qbs, qbb, qbm, qbv,
                                                     kb, kbs, kbb, kbm, kbv,
                                                     qhB, qlB, khB, klB);
    k_gemm_vv2 <<<dim3(64, 4, NB), 256, 0, stream>>>(x, vw, vb, svw, svb, v2T, vhi, vlo);
    k_reduce_v2<<<dim3(4096),      256, 0, stream>>>(v2T, smo);
    k_spatial  <<<dim3(NB),        256, 0, stream>>>(smo, scw, scb, sbs, sbb, sbm, sbv, Amat);
    k_xstats   <<<dim3(NC, NB),    256, 0, stream>>>(x, smean, smax);
    k_gate     <<<dim3(NB),        256, 0, stream>>>(smean, smax, cw1, cb1, cw2, cb2, gate);
    k_softstats<<<dim3(256, NB),   64,  0, stream>>>(qhB, qlB, khB, klB, mxp, rlp);
    k_flash    <<<dim3(512),       256, 0, stream>>>(qhB, qlB, khB, klB, vhi, vlo,
                                                     mxp, rlp, w0, w1);
    k_final    <<<dim3(64, NB),    256, 0, stream>>>(x, w0, w1, gate, Amat, gm,
                                                     (float*)d_out);
}

// Round 4
// 533.260 us; speedup vs baseline: 1.1129x; 1.1129x over previous
//
#include <hip/hip_runtime.h>
#include <math.h>

#define NB 4
#define NC 256
#define NHW 4096
#define NC8 32
#define NC2 128

typedef unsigned short u16;
typedef __attribute__((ext_vector_type(8))) short s8v;   // 8 x bf16 (MFMA A/B frag)
typedef __attribute__((ext_vector_type(4))) short s4v;   // 4 x bf16
typedef __attribute__((ext_vector_type(4))) float f4v;   // 4 x f32  (MFMA C/D frag)

__device__ __forceinline__ u16 f2bf(float x) {
    unsigned int u = __builtin_bit_cast(unsigned int, x);
    u += 0x7FFFu + ((u >> 16) & 1u);          // RNE
    return (u16)(u >> 16);
}
__device__ __forceinline__ float bf2f(u16 h) {
    unsigned int u = ((unsigned int)h) << 16;
    return __builtin_bit_cast(float, u);
}
__device__ __forceinline__ s8v ld_sp(const u16* p) {   // 8B-aligned 16B LDS read (split)
    s4v a = *(const s4v*)p;
    s4v b = *(const s4v*)(p + 4);
    return __builtin_shufflevector(a, b, 0, 1, 2, 3, 4, 5, 6, 7);
}

#define MFMA16(a, b, c) __builtin_amdgcn_mfma_f32_16x16x32_bf16((a), (b), (c), 0, 0, 0)

// ---------------------------------------------------------------------------
// K1: conv3x3 partials. grid (16 co-groups of 4, 4 ci-chunks of 64, B).
// ---------------------------------------------------------------------------
__global__ __launch_bounds__(256) void k_conv_qk(
    const float* __restrict__ x,
    const float* __restrict__ qw, const float* __restrict__ kw,
    float* __restrict__ part)
{
    __shared__ float plane[2][64 * 65];
    const int cog = blockIdx.x;
    const int cic = blockIdx.y;
    const int b   = blockIdx.z;
    const int t   = threadIdx.x;
    const int co0 = cog * 4;
    const bool isq = co0 < NC8;
    const int oc0 = isq ? co0 : co0 - NC8;
    const float* wsel = isq ? qw : kw;
    const int ci0 = cic * 64;
    const int r  = t >> 2;
    const int c0 = (t & 3) * 16;
    float acc[4][16];
#pragma unroll
    for (int j = 0; j < 4; ++j)
#pragma unroll
        for (int q = 0; q < 16; ++q) acc[j][q] = 0.f;

    const float* xb = x + (size_t)b * NC * NHW;
    float4 pf[4];
    {
        const float4* src = (const float4*)(xb + (size_t)ci0 * NHW);
#pragma unroll
        for (int u = 0; u < 4; ++u) pf[u] = src[t + 256 * u];
    }
    for (int ci = ci0; ci < ci0 + 64; ++ci) {
        const int cur = ci & 1;
#pragma unroll
        for (int u = 0; u < 4; ++u) {
            int g  = (t + 256 * u) << 2;
            int rr = g >> 6, cc = g & 63;
            float* p = &plane[cur][rr * 65 + cc];
            p[0] = pf[u].x; p[1] = pf[u].y; p[2] = pf[u].z; p[3] = pf[u].w;
        }
        __syncthreads();
        if (ci + 1 < ci0 + 64) {
            const float4* src = (const float4*)(xb + (size_t)(ci + 1) * NHW);
#pragma unroll
            for (int u = 0; u < 4; ++u) pf[u] = src[t + 256 * u];
        }
        float w9[4][9];
#pragma unroll
        for (int j = 0; j < 4; ++j)
#pragma unroll
            for (int u = 0; u < 9; ++u)
                w9[j][u] = wsel[((size_t)(oc0 + j) * NC + ci) * 9 + u];
#pragma unroll
        for (int dy = 0; dy < 3; ++dy) {
            int rr = r + dy - 1;
            if (rr >= 0 && rr <= 63) {
                const float* row = &plane[cur][rr * 65];
                float tv[18];
#pragma unroll
                for (int jj = 0; jj < 18; ++jj) {
                    int cc = c0 + jj - 1;
                    tv[jj] = (cc >= 0 && cc < 64) ? row[cc] : 0.f;
                }
#pragma unroll
                for (int j = 0; j < 4; ++j) {
                    float wa = w9[j][dy * 3 + 0], wb = w9[j][dy * 3 + 1], wc = w9[j][dy * 3 + 2];
#pragma unroll
                    for (int q = 0; q < 16; ++q)
                        acc[j][q] += wa * tv[q] + wb * tv[q + 1] + wc * tv[q + 2];
                }
            }
        }
        __syncthreads();
    }
    float* pp = part + (((size_t)(cic * 4 + b) * 64 + co0) * NHW) + r * 64 + c0;
#pragma unroll
    for (int j = 0; j < 4; ++j)
#pragma unroll
        for (int q4 = 0; q4 < 4; ++q4) {
            float4 o;
            o.x = acc[j][q4 * 4 + 0]; o.y = acc[j][q4 * 4 + 1];
            o.z = acc[j][q4 * 4 + 2]; o.w = acc[j][q4 * 4 + 3];
            *(float4*)(pp + (size_t)j * NHW + q4 * 4) = o;
        }
}

// ---------------------------------------------------------------------------
// K1b: sum partials + bias + bn + relu -> q/k bf16 hi/lo, [b][pixel][32ch].
// ---------------------------------------------------------------------------
__global__ __launch_bounds__(256) void k_qk_finish(
    const float* __restrict__ part,
    const float* __restrict__ qb, const float* __restrict__ qbs, const float* __restrict__ qbb,
    const float* __restrict__ qbm, const float* __restrict__ qbv,
    const float* __restrict__ kb, const float* __restrict__ kbs, const float* __restrict__ kbb,
    const float* __restrict__ kbm, const float* __restrict__ kbv,
    u16* __restrict__ qh, u16* __restrict__ ql,
    u16* __restrict__ kh, u16* __restrict__ kl)
{
    const int t = threadIdx.x;
    const int b = blockIdx.y;
    const int n = blockIdx.x * 64 + (t & 63);
    const int coq = t >> 6;
    const int cb2 = coq * 16;
    float s[16];
#pragma unroll
    for (int j = 0; j < 16; ++j) s[j] = 0.f;
#pragma unroll
    for (int cic = 0; cic < 4; ++cic)
#pragma unroll
        for (int j = 0; j < 16; ++j)
            s[j] += part[(((size_t)(cic * 4 + b)) * 64 + cb2 + j) * NHW + n];
    const bool isq = coq < 2;
    u16 hi[16], lo[16];
#pragma unroll
    for (int j = 0; j < 16; ++j) {
        int oc = (coq & 1) * 16 + j;
        float cbv = isq ? qb[oc]  : kb[oc];
        float sv  = isq ? qbs[oc] : kbs[oc];
        float bbv = isq ? qbb[oc] : kbb[oc];
        float mv  = isq ? qbm[oc] : kbm[oc];
        float vv  = isq ? qbv[oc] : kbv[oc];
        float inv = rsqrtf(vv + 1e-5f);
        float scale = inv * sv;
        float shift = (cbv - mv) * scale + bbv;
        float y = fmaxf(s[j] * scale + shift, 0.f);
        hi[j] = f2bf(y);
        lo[j] = f2bf(y - bf2f(hi[j]));
    }
    u16* dh = isq ? qh : kh;
    u16* dl = isq ? ql : kl;
    size_t base = ((size_t)b * NHW + n) * 32 + (coq & 1) * 16;
    uint4 ph0, ph1, pl0, pl1;
    ph0.x = (unsigned)hi[0]  | ((unsigned)hi[1]  << 16);
    ph0.y = (unsigned)hi[2]  | ((unsigned)hi[3]  << 16);
    ph0.z = (unsigned)hi[4]  | ((unsigned)hi[5]  << 16);
    ph0.w = (unsigned)hi[6]  | ((unsigned)hi[7]  << 16);
    ph1.x = (unsigned)hi[8]  | ((unsigned)hi[9]  << 16);
    ph1.y = (unsigned)hi[10] | ((unsigned)hi[11] << 16);
    ph1.z = (unsigned)hi[12] | ((unsigned)hi[13] << 16);
    ph1.w = (unsigned)hi[14] | ((unsigned)hi[15] << 16);
    pl0.x = (unsigned)lo[0]  | ((unsigned)lo[1]  << 16);
    pl0.y = (unsigned)lo[2]  | ((unsigned)lo[3]  << 16);
    pl0.z = (unsigned)lo[4]  | ((unsigned)lo[5]  << 16);
    pl0.w = (unsigned)lo[6]  | ((unsigned)lo[7]  << 16);
    pl1.x = (unsigned)lo[8]  | ((unsigned)lo[9]  << 16);
    pl1.y = (unsigned)lo[10] | ((unsigned)lo[11] << 16);
    pl1.z = (unsigned)lo[12] | ((unsigned)lo[13] << 16);
    pl1.w = (unsigned)lo[14] | ((unsigned)lo[15] << 16);
    *(uint4*)&dh[base]     = ph0;
    *(uint4*)&dh[base + 8] = ph1;
    *(uint4*)&dl[base]     = pl0;
    *(uint4*)&dl[base + 8] = pl1;
}

// ---------------------------------------------------------------------------
// K2: dual 1x1 conv: v2T fp32 + v bf16 hi/lo [b][o][n].
// ---------------------------------------------------------------------------
__global__ __launch_bounds__(256) void k_gemm_vv2(
    const float* __restrict__ x,
    const float* __restrict__ vw, const float* __restrict__ vb,
    const float* __restrict__ sw, const float* __restrict__ sb,
    float* __restrict__ v2T, u16* __restrict__ vhi, u16* __restrict__ vlo)
{
    __shared__ float Ax[16 * 68];
    __shared__ float Bw1[16 * 68];
    __shared__ float Bw2[16 * 68];
    const int t  = threadIdx.x;
    const int n0 = blockIdx.x * 64;
    const int o0 = blockIdx.y * 64;
    const int b  = blockIdx.z;
    const int ni = t & 15, oi = t >> 4;
    float a1[4][4], a2[4][4];
#pragma unroll
    for (int i = 0; i < 4; ++i)
#pragma unroll
        for (int j = 0; j < 4; ++j) { a1[i][j] = 0.f; a2[i][j] = 0.f; }

    const int sk  = t >> 4;
    const int sf  = t & 15;
    const int so  = t & 63;
    const int skq = t >> 6;
    const float* xb = x + ((size_t)b * NC) * NHW + n0;

    float4 ax = *(const float4*)(xb + (size_t)sk * NHW + sf * 4);
    float4 f1 = *(const float4*)(vw + (size_t)(o0 + so) * NC + skq * 4);
    float4 f2 = *(const float4*)(sw + (size_t)(o0 + so) * NC + skq * 4);

    for (int c0 = 0; c0 < NC; c0 += 16) {
        *(float4*)&Ax[sk * 68 + sf * 4] = ax;
        Bw1[(skq * 4 + 0) * 68 + so] = f1.x;
        Bw1[(skq * 4 + 1) * 68 + so] = f1.y;
        Bw1[(skq * 4 + 2) * 68 + so] = f1.z;
        Bw1[(skq * 4 + 3) * 68 + so] = f1.w;
        Bw2[(skq * 4 + 0) * 68 + so] = f2.x;
        Bw2[(skq * 4 + 1) * 68 + so] = f2.y;
        Bw2[(skq * 4 + 2) * 68 + so] = f2.z;
        Bw2[(skq * 4 + 3) * 68 + so] = f2.w;
        __syncthreads();
        if (c0 + 16 < NC) {
            ax = *(const float4*)(xb + (size_t)(c0 + 16 + sk) * NHW + sf * 4);
            f1 = *(const float4*)(vw + (size_t)(o0 + so) * NC + c0 + 16 + skq * 4);
            f2 = *(const float4*)(sw + (size_t)(o0 + so) * NC + c0 + 16 + skq * 4);
        }
#pragma unroll
        for (int k = 0; k < 16; ++k) {
            float4 af = *(const float4*)&Ax[k * 68 + ni * 4];
            float4 g1 = *(const float4*)&Bw1[k * 68 + oi * 4];
            float4 g2 = *(const float4*)&Bw2[k * 68 + oi * 4];
            const float* ap = (const float*)&af;
            const float* p1 = (const float*)&g1;
            const float* p2 = (const float*)&g2;
#pragma unroll
            for (int i = 0; i < 4; ++i)
#pragma unroll
                for (int j = 0; j < 4; ++j) {
                    a1[i][j] += ap[i] * p1[j];
                    a2[i][j] += ap[i] * p2[j];
                }
        }
        __syncthreads();
    }
    float vb4[4], sb4[4];
#pragma unroll
    for (int j = 0; j < 4; ++j) { vb4[j] = vb[o0 + oi * 4 + j]; sb4[j] = sb[o0 + oi * 4 + j]; }
#pragma unroll
    for (int i = 0; i < 4; ++i) {
        size_t idx = ((size_t)b * NHW + n0 + ni * 4 + i) * NC + o0 + oi * 4;
        float4 o2v;
        o2v.x = a2[i][0] + sb4[0]; o2v.y = a2[i][1] + sb4[1];
        o2v.z = a2[i][2] + sb4[2]; o2v.w = a2[i][3] + sb4[3];
        *(float4*)&v2T[idx] = o2v;
    }
#pragma unroll
    for (int j = 0; j < 4; ++j) {
        u16 h[4], l[4];
#pragma unroll
        for (int i = 0; i < 4; ++i) {
            float y = a1[i][j] + vb4[j];
            h[i] = f2bf(y);
            l[i] = f2bf(y - bf2f(h[i]));
        }
        size_t vi = ((size_t)b * NC + o0 + oi * 4 + j) * NHW + n0 + ni * 4;
        uint2 uh, ul;
        uh.x = (unsigned)h[0] | ((unsigned)h[1] << 16);
        uh.y = (unsigned)h[2] | ((unsigned)h[3] << 16);
        ul.x = (unsigned)l[0] | ((unsigned)l[1] << 16);
        ul.y = (unsigned)l[2] | ((unsigned)l[3] << 16);
        *(uint2*)&vhi[vi] = uh;
        *(uint2*)&vlo[vi] = ul;
    }
}

// ---------------------------------------------------------------------------
// K3: channel max/mean of v2T rows -> smo[b,{max,mean},n]
// ---------------------------------------------------------------------------
__global__ __launch_bounds__(256) void k_reduce_v2(const float* __restrict__ v2T,
                                                   float* __restrict__ smo)
{
    const int t = threadIdx.x;
    const int lane = t & 63, wv = t >> 6;
    const int row = blockIdx.x * 4 + wv;
    float4 f = ((const float4*)(v2T + (size_t)row * NC))[lane];
    float mx = fmaxf(fmaxf(f.x, f.y), fmaxf(f.z, f.w));
    float sm = f.x + f.y + f.z + f.w;
#pragma unroll
    for (int off = 32; off; off >>= 1) {
        mx = fmaxf(mx, __shfl_down(mx, off));
        sm += __shfl_down(sm, off);
    }
    if (lane == 0) {
        int b = row >> 12, n = row & 4095;
        smo[((size_t)b * 2 + 0) * NHW + n] = mx;
        smo[((size_t)b * 2 + 1) * NHW + n] = sm * (1.f / NC);
    }
}

// ---------------------------------------------------------------------------
// K4: conv3x3(2ch->1) + bn + row softmax -> Amat[b,w,k]
// ---------------------------------------------------------------------------
__global__ __launch_bounds__(256) void k_spatial(
    const float* __restrict__ smo, const float* __restrict__ scw,
    const float* __restrict__ scb, const float* __restrict__ sbs,
    const float* __restrict__ sbb2, const float* __restrict__ sbm,
    const float* __restrict__ sbv, float* __restrict__ Amat)
{
    __shared__ float ch[2][64 * 68];
    __shared__ float lg[64 * 68];
    const int t = threadIdx.x;
    const int b = blockIdx.x;
#pragma unroll
    for (int u = 0; u < 8; ++u) {
        int g  = t + 256 * u;
        int c  = g >> 10, gi = g & 1023;
        int row = gi >> 4, col4 = (gi & 15) * 4;
        float4 f = ((const float4*)(smo + ((size_t)b * 2 + c) * NHW))[gi];
        *(float4*)&ch[c][row * 68 + col4] = f;
    }
    __syncthreads();
    float w9[2][9];
#pragma unroll
    for (int ic = 0; ic < 2; ++ic)
#pragma unroll
        for (int j = 0; j < 9; ++j) w9[ic][j] = scw[ic * 9 + j];
    float A0, Bsh;
    {
        float inv = rsqrtf(sbv[0] + 1e-5f);
        A0  = inv * sbs[0];
        Bsh = (scb[0] - sbm[0]) * A0 + sbb2[0];
    }
#pragma unroll
    for (int u = 0; u < 16; ++u) {
        int px = t + 256 * u;
        int h = px >> 6, w = px & 63;
        float acc = 0.f;
#pragma unroll
        for (int ic = 0; ic < 2; ++ic)
#pragma unroll
            for (int dy = 0; dy < 3; ++dy) {
                int rr = h + dy - 1;
                if (rr < 0 || rr > 63) continue;
#pragma unroll
                for (int dx = 0; dx < 3; ++dx) {
                    int cc = w + dx - 1;
                    if (cc < 0 || cc > 63) continue;
                    acc += w9[ic][dy * 3 + dx] * ch[ic][rr * 68 + cc];
                }
            }
        lg[h * 68 + w] = acc * A0 + Bsh;
    }
    __syncthreads();
    if (t < 64) {
        float M = -INFINITY;
        for (int k2 = 0; k2 < 64; ++k2) M = fmaxf(M, lg[t * 68 + k2]);
        float L = 0.f;
        for (int k2 = 0; k2 < 64; ++k2) L += __expf(lg[t * 68 + k2] - M);
        float rli = 1.f / L;
        for (int k2 = 0; k2 < 64; ++k2)
            Amat[(size_t)b * NHW + t * 64 + k2] = __expf(lg[t * 68 + k2] - M) * rli;
    }
}

// ---------------------------------------------------------------------------
// K5: per-(b,c) spatial mean & max of x
// ---------------------------------------------------------------------------
__global__ __launch_bounds__(256) void k_xstats(const float* __restrict__ x,
                                                float* __restrict__ smean,
                                                float* __restrict__ smax)
{
    const int t = threadIdx.x;
    const int c = blockIdx.x, b = blockIdx.y;
    const float* row = x + ((size_t)b * NC + c) * NHW;
    float s = 0.f, m = -INFINITY;
#pragma unroll
    for (int u = 0; u < 4; ++u) {
        float4 f = ((const float4*)row)[t + 256 * u];
        s += f.x + f.y + f.z + f.w;
        m = fmaxf(m, fmaxf(fmaxf(f.x, f.y), fmaxf(f.z, f.w)));
    }
    __shared__ float red[8];
    const int lane = t & 63, wv = t >> 6;
#pragma unroll
    for (int off = 32; off; off >>= 1) {
        s += __shfl_down(s, off);
        m = fmaxf(m, __shfl_down(m, off));
    }
    if (lane == 0) { red[wv] = s; red[4 + wv] = m; }
    __syncthreads();
    if (t == 0) {
        float S = red[0] + red[1] + red[2] + red[3];
        float M = fmaxf(fmaxf(red[4], red[5]), fmaxf(red[6], red[7]));
        smean[b * NC + c] = S * (1.f / NHW);
        smax[b * NC + c]  = M;
    }
}

// ---------------------------------------------------------------------------
// K6: channel gate
// ---------------------------------------------------------------------------
__global__ __launch_bounds__(256) void k_gate(
    const float* __restrict__ smean, const float* __restrict__ smax,
    const float* __restrict__ w1, const float* __restrict__ b1,
    const float* __restrict__ w2, const float* __restrict__ b2,
    float* __restrict__ gate)
{
    __shared__ float smL[256], sxL[256], hL[256];
    const int t = threadIdx.x;
    const int b = blockIdx.x;
    smL[t] = smean[b * NC + t];
    sxL[t] = smax[b * NC + t];
    __syncthreads();
    {
        const int j = t & 127;
        const float* in = (t < 128) ? smL : sxL;
        const float* wr = w1 + (size_t)j * NC;
        float acc = b1[j];
        for (int c = 0; c < NC; c += 4) {
            float4 f = *(const float4*)(wr + c);
            acc += f.x * in[c] + f.y * in[c + 1] + f.z * in[c + 2] + f.w * in[c + 3];
        }
        hL[t] = fmaxf(acc, 0.f);
    }
    __syncthreads();
    {
        const float* wr = w2 + (size_t)t * NC2;
        float acc = 2.f * b2[t];
        for (int j = 0; j < NC2; j += 4) {
            float4 f = *(const float4*)(wr + j);
            acc += f.x * (hL[j]     + hL[128 + j])
                 + f.y * (hL[j + 1] + hL[129 + j])
                 + f.z * (hL[j + 2] + hL[130 + j])
                 + f.w * (hL[j + 3] + hL[131 + j]);
        }
        gate[b * NC + t] = 1.f / (1.f + __expf(-acc));
    }
}

// ---------------------------------------------------------------------------
// K7: softmax row stats via bf16-split MFMA (swapped: S^T = K^T Q).
// ---------------------------------------------------------------------------
__global__ __launch_bounds__(64) void k_softstats(
    const u16* __restrict__ qh, const u16* __restrict__ ql,
    const u16* __restrict__ kh, const u16* __restrict__ kl,
    float* __restrict__ mx, float* __restrict__ rl)
{
    const int t  = threadIdx.x;
    const int li = t & 15, g = t >> 4;
    const int n0 = blockIdx.x * 16;
    const int b  = blockIdx.y;
    const size_t qoff = ((size_t)b * NHW + n0 + li) * 32 + g * 8;
    const s8v qfh = *(const s8v*)&qh[qoff];
    const s8v qfl = *(const s8v*)&ql[qoff];
    const size_t kb0 = ((size_t)b * NHW + li) * 32 + g * 8;
    s8v ka0 = *(const s8v*)&kh[kb0];
    s8v ka1 = *(const s8v*)&kh[kb0 + 512];
    s8v la0 = *(const s8v*)&kl[kb0];
    s8v la1 = *(const s8v*)&kl[kb0 + 512];
    float mrun = -INFINITY, lrun = 0.f;
    for (int it = 0; it < 128; ++it) {
        f4v c0 = {0.f, 0.f, 0.f, 0.f}, c1 = {0.f, 0.f, 0.f, 0.f};
        c0 = MFMA16(ka0, qfh, c0); c0 = MFMA16(ka0, qfl, c0); c0 = MFMA16(la0, qfh, c0);
        c1 = MFMA16(ka1, qfh, c1); c1 = MFMA16(ka1, qfl, c1); c1 = MFMA16(la1, qfh, c1);
        if (it + 1 < 128) {
            size_t o = kb0 + (size_t)(it + 1) * 1024;
            ka0 = *(const s8v*)&kh[o];
            ka1 = *(const s8v*)&kh[o + 512];
            la0 = *(const s8v*)&kl[o];
            la1 = *(const s8v*)&kl[o + 512];
        }
        float tmax = fmaxf(fmaxf(fmaxf(c0[0], c0[1]), fmaxf(c0[2], c0[3])),
                           fmaxf(fmaxf(c1[0], c1[1]), fmaxf(c1[2], c1[3])));
        tmax = fmaxf(tmax, __shfl_xor(tmax, 16));
        tmax = fmaxf(tmax, __shfl_xor(tmax, 32));
        float nm = fmaxf(mrun, tmax);
        float ls = 0.f;
#pragma unroll
        for (int r = 0; r < 4; ++r) ls += __expf(c0[r] - nm);
#pragma unroll
        for (int r = 0; r < 4; ++r) ls += __expf(c1[r] - nm);
        ls += __shfl_xor(ls, 16);
        ls += __shfl_xor(ls, 32);
        lrun = lrun * __expf(mrun - nm) + ls;
        mrun = nm;
    }
    if (g == 0) {
        mx[(size_t)b * NHW + n0 + li] = mrun;
        rl[(size_t)b * NHW + n0 + li] = 1.f / lrun;
    }
}

// ---------------------------------------------------------------------------
// K8: flash pass B. Waves own c-ranges; V B-frags loaded DIRECTLY from
// global (L2-resident via XCD swizzle) -- no V LDS. Only P crosses waves
// via tiny double-buffered Sp (9KB). One barrier per iter.
// Per iter per wave: 6 QK MFMA + 32 PV MFMA (P-lo dropped), 12 global b128,
// 2 LDS b64 writes + 8 LDS b64 reads.
// ---------------------------------------------------------------------------
__global__ __launch_bounds__(256, 2) void k_flash(
    const u16* __restrict__ qh, const u16* __restrict__ ql,
    const u16* __restrict__ kh, const u16* __restrict__ kl,
    const u16* __restrict__ vhi, const u16* __restrict__ vlo,
    const float* __restrict__ mx, const float* __restrict__ rl,
    float* __restrict__ w0, float* __restrict__ w1)
{
    __shared__ __align__(16) u16 Sp[2][4][16 * 36];   // [buf][ng][row 16 x 36]
    const int t = threadIdx.x;
    const int bid = blockIdx.x;
    const int v   = (bid & 7) * 64 + (bid >> 3);      // XCD swizzle (512 = 8*64)
    const int n0  = (v & 63) * 64;
    const int mh  = (v >> 6) & 1;
    const int b   = v >> 7;
    const int mbase = mh * 2048;
    const int li = t & 15, g = (t >> 4) & 3, wv = t >> 6;

    // Q B-frags for this wave's n-group (ng == wv)
    const size_t qoff = ((size_t)b * NHW + n0 + wv * 16 + li) * 32 + g * 8;
    const s8v qfh = *(const s8v*)&qh[qoff];
    const s8v qfl = *(const s8v*)&ql[qoff];
    const float mxv = mx[(size_t)b * NHW + n0 + wv * 16 + li];
    const float rlv = rl[(size_t)b * NHW + n0 + wv * 16 + li];

    f4v acc[4][4];                                    // [ng][ct]
#pragma unroll
    for (int i = 0; i < 4; ++i)
#pragma unroll
        for (int j = 0; j < 4; ++j) { f4v z = {0.f, 0.f, 0.f, 0.f}; acc[i][j] = z; }

    // K A-frag prefetch (it = 0)
    const size_t kb0 = ((size_t)b * NHW + mbase + li) * 32 + g * 8;
    s8v ka0 = *(const s8v*)&kh[kb0];
    s8v ka1 = *(const s8v*)&kh[kb0 + 512];
    s8v la0 = *(const s8v*)&kl[kb0];
    s8v la1 = *(const s8v*)&kl[kb0 + 512];

    // V B-frag prefetch (it = 0): wave owns c in [wv*64, wv*64+64)
    const size_t vb0 = ((size_t)b * NC + wv * 64 + li) * NHW + mbase + g * 8;
    s8v vfh[4], vfl[4];
#pragma unroll
    for (int ct = 0; ct < 4; ++ct) {
        vfh[ct] = *(const s8v*)&vhi[vb0 + (size_t)ct * 16 * NHW];
        vfl[ct] = *(const s8v*)&vlo[vb0 + (size_t)ct * 16 * NHW];
    }

    for (int it = 0; it < 64; ++it) {
        // ---- QK: S^T for this wave's 16 n x 32 m ----
        f4v c0 = {0.f, 0.f, 0.f, 0.f}, c1 = {0.f, 0.f, 0.f, 0.f};
        c0 = MFMA16(ka0, qfh, c0); c0 = MFMA16(ka0, qfl, c0); c0 = MFMA16(la0, qfh, c0);
        c1 = MFMA16(ka1, qfh, c1); c1 = MFMA16(ka1, qfl, c1); c1 = MFMA16(la1, qfh, c1);
        {   // K prefetch it+1 (tail over-read stays inside workspace)
            size_t o = kb0 + (size_t)(it + 1) * 1024;
            ka0 = *(const s8v*)&kh[o];
            ka1 = *(const s8v*)&kh[o + 512];
            la0 = *(const s8v*)&kl[o];
            la1 = *(const s8v*)&kl[o + 512];
        }
        // ---- P = exp(S - mx) * rl (hi only) -> Sp ----
        u16 h0[4], h1[4];
#pragma unroll
        for (int r = 0; r < 4; ++r) {
            h0[r] = f2bf(__expf(c0[r] - mxv) * rlv);
            h1[r] = f2bf(__expf(c1[r] - mxv) * rlv);
        }
        u16* sp = &Sp[it & 1][wv][0];
        uint2 uw0, uw1;
        uw0.x = (unsigned)h0[0] | ((unsigned)h0[1] << 16);
        uw0.y = (unsigned)h0[2] | ((unsigned)h0[3] << 16);
        uw1.x = (unsigned)h1[0] | ((unsigned)h1[1] << 16);
        uw1.y = (unsigned)h1[2] | ((unsigned)h1[3] << 16);
        *(uint2*)&sp[li * 36 + g * 4]      = uw0;     // m = g*4..+3
        *(uint2*)&sp[li * 36 + 16 + g * 4] = uw1;     // m = 16+g*4..+3
        __syncthreads();
        // ---- P A-frags for all 4 n-groups ----
        s8v pa0 = ld_sp(&Sp[it & 1][0][li * 36 + g * 8]);
        s8v pa1 = ld_sp(&Sp[it & 1][1][li * 36 + g * 8]);
        s8v pa2 = ld_sp(&Sp[it & 1][2][li * 36 + g * 8]);
        s8v pa3 = ld_sp(&Sp[it & 1][3][li * 36 + g * 8]);
        // ---- PV: acc[ng][ct] += P[ng] x V[ct] (2-term split) ----
#pragma unroll
        for (int ct = 0; ct < 4; ++ct) {
            acc[0][ct] = MFMA16(pa0, vfh[ct], acc[0][ct]);
            acc[0][ct] = MFMA16(pa0, vfl[ct], acc[0][ct]);
            acc[1][ct] = MFMA16(pa1, vfh[ct], acc[1][ct]);
            acc[1][ct] = MFMA16(pa1, vfl[ct], acc[1][ct]);
            acc[2][ct] = MFMA16(pa2, vfh[ct], acc[2][ct]);
            acc[2][ct] = MFMA16(pa2, vfl[ct], acc[2][ct]);
            acc[3][ct] = MFMA16(pa3, vfh[ct], acc[3][ct]);
            acc[3][ct] = MFMA16(pa3, vfl[ct], acc[3][ct]);
        }
        {   // V prefetch it+1 (tail over-read stays inside workspace)
            size_t o = vb0 + (size_t)(it + 1) * 32;
#pragma unroll
            for (int ct = 0; ct < 4; ++ct) {
                vfh[ct] = *(const s8v*)&vhi[o + (size_t)ct * 16 * NHW];
                vfl[ct] = *(const s8v*)&vlo[o + (size_t)ct * 16 * NHW];
            }
        }
    }
    float* wout = (mh == 0) ? w0 : w1;
#pragma unroll
    for (int ng = 0; ng < 4; ++ng)
#pragma unroll
        for (int ct = 0; ct < 4; ++ct)
#pragma unroll
            for (int r = 0; r < 4; ++r)
                wout[((size_t)b * NHW + n0 + ng * 16 + g * 4 + r) * NC
                     + wv * 64 + ct * 16 + li] = acc[ng][ct][r];
}

// ---------------------------------------------------------------------------
// K9: out = gamma*(w0+w1) + x*(1+gate) + x @ A  -- LDS-tiled mini-GEMM
// block = (h, b). A[64w][64k] staged once; x chunk [64w][64c] transposed.
// ---------------------------------------------------------------------------
__global__ __launch_bounds__(256) void k_final(
    const float* __restrict__ x, const float* __restrict__ w0,
    const float* __restrict__ w1, const float* __restrict__ gate,
    const float* __restrict__ Amat, const float* __restrict__ gamma,
    float* __restrict__ out)
{
    __shared__ float As[64 * 65];
    __shared__ float xs[64 * 65];
    const int t = threadIdx.x;
    const int h = blockIdx.x, b = blockIdx.y;
    const float g0 = gamma[0];
    const int kq = t >> 4;       // 0..15 -> k = kq*4..+3
    const int cq = t & 15;       // 0..15 -> c-local = cq*4..+3
#pragma unroll
    for (int u = 0; u < 4; ++u) {
        int gidx = t + 256 * u;              // f4 index over 1024
        int w = gidx >> 4, k4 = (gidx & 15) * 4;
        float4 f = ((const float4*)(Amat + (size_t)b * NHW))[gidx];
        *(float4*)&As[w * 65 + k4] = f;
    }
    for (int ch = 0; ch < 4; ++ch) {
        __syncthreads();                     // protect xs (and cover As on ch=0)
#pragma unroll
        for (int u = 0; u < 4; ++u) {
            int gidx = t + 256 * u;
            int c = gidx >> 4, w4 = (gidx & 15) * 4;
            float4 f = *(const float4*)(x + ((size_t)(b * NC) + ch * 64 + c) * NHW + h * 64 + w4);
            xs[(w4 + 0) * 65 + c] = f.x;
            xs[(w4 + 1) * 65 + c] = f.y;
            xs[(w4 + 2) * 65 + c] = f.z;
            xs[(w4 + 3) * 65 + c] = f.w;
        }
        __syncthreads();
        float acc[4][4];
#pragma unroll
        for (int i = 0; i < 4; ++i)
#pragma unroll
            for (int j = 0; j < 4; ++j) acc[i][j] = 0.f;
        for (int w = 0; w < 64; ++w) {
            float4 av = *(const float4*)&As[w * 65 + kq * 4];
            float4 xv = *(const float4*)&xs[w * 65 + cq * 4];
            const float* ap = (const float*)&av;
            const float* xp = (const float*)&xv;
#pragma unroll
            for (int i = 0; i < 4; ++i)
#pragma unroll
                for (int j = 0; j < 4; ++j)
                    acc[i][j] += xp[i] * ap[j];
        }
#pragma unroll
        for (int i = 0; i < 4; ++i) {
            const int c = ch * 64 + cq * 4 + i;
            const float gt1 = 1.f + gate[b * NC + c];
#pragma unroll
            for (int j = 0; j < 4; ++j) {
                const int k = kq * 4 + j;
                const int n = h * 64 + k;
                const float xv = xs[k * 65 + cq * 4 + i];
                const size_t widx = ((size_t)b * NHW + n) * NC + c;
                const float wsum = w0[widx] + w1[widx];
                out[((size_t)(b * NC + c)) * NHW + n] = g0 * wsum + xv * gt1 + acc[i][j];
            }
        }
    }
}

// ---------------------------------------------------------------------------
extern "C" void kernel_launch(void* const* d_in, const int* in_sizes, int n_in,
                              void* d_out, int out_size, void* d_ws, size_t ws_size,
                              hipStream_t stream)
{
    const float* x    = (const float*)d_in[0];
    const float* qw   = (const float*)d_in[1];
    const float* qb   = (const float*)d_in[2];
    const float* qbs  = (const float*)d_in[3];
    const float* qbb  = (const float*)d_in[4];
    const float* qbm  = (const float*)d_in[5];
    const float* qbv  = (const float*)d_in[6];
    const float* kw   = (const float*)d_in[7];
    const float* kb   = (const float*)d_in[8];
    const float* kbs  = (const float*)d_in[9];
    const float* kbb  = (const float*)d_in[10];
    const float* kbm  = (const float*)d_in[11];
    const float* kbv  = (const float*)d_in[12];
    const float* vw   = (const float*)d_in[13];
    const float* vb   = (const float*)d_in[14];
    const float* gm   = (const float*)d_in[15];
    const float* cw1  = (const float*)d_in[16];
    const float* cb1  = (const float*)d_in[17];
    const float* cw2  = (const float*)d_in[18];
    const float* cb2  = (const float*)d_in[19];
    const float* svw  = (const float*)d_in[20];
    const float* svb  = (const float*)d_in[21];
    const float* scw  = (const float*)d_in[22];
    const float* scb  = (const float*)d_in[23];
    const float* sbs  = (const float*)d_in[24];
    const float* sbb  = (const float*)d_in[25];
    const float* sbm  = (const float*)d_in[26];
    const float* sbv  = (const float*)d_in[27];

    float* ws    = (float*)d_ws;
    float* part  = ws;                      // 4,194,304 f  (reused as w0)
    float* w0    = ws;
    float* v2T   = ws + 4194304;            // 4,194,304 f  (reused as w1)
    float* w1    = ws + 4194304;
    u16*   vhi   = (u16*)(ws + 8388608);    // 4,194,304 u16
    u16*   vlo   = (u16*)(ws + 10485760);
    u16*   qhB   = (u16*)(ws + 12582912);   //   524,288 u16
    u16*   qlB   = (u16*)(ws + 12845056);
    u16*   khB   = (u16*)(ws + 13107200);
    u16*   klB   = (u16*)(ws + 13369344);
    float* mxp   = ws + 13631488;
    float* rlp   = ws + 13647872;
    float* smean = ws + 13664256;
    float* smax  = ws + 13665280;
    float* gate  = ws + 13666304;
    float* smo   = ws + 13667328;
    float* Amat  = ws + 13700096;
    // total 13,716,480 floats ~= 54.9 MB

    k_conv_qk  <<<dim3(16, 4, NB), 256, 0, stream>>>(x, qw, kw, part);
    k_qk_finish<<<dim3(64, NB),    256, 0, stream>>>(part, qb, qbs, qbb, qbm, qbv,
                                                     kb, kbs, kbb, kbm, kbv,
                                                     qhB, qlB, khB, klB);
    k_gemm_vv2 <<<dim3(64, 4, NB), 256, 0, stream>>>(x, vw, vb, svw, svb, v2T, vhi, vlo);
    k_reduce_v2<<<dim3(4096),      256, 0, stream>>>(v2T, smo);
    k_spatial  <<<dim3(NB),        256, 0, stream>>>(smo, scw, scb, sbs, sbb, sbm, sbv, Amat);
    k_xstats   <<<dim3(NC, NB),    256, 0, stream>>>(x, smean, smax);
    k_gate     <<<dim3(NB),        256, 0, stream>>>(smean, smax, cw1, cb1, cw2, cb2, gate);
    k_softstats<<<dim3(256, NB),   64,  0, stream>>>(qhB, qlB, khB, klB, mxp, rlp);
    k_flash    <<<dim3(512),       256, 0, stream>>>(qhB, qlB, khB, klB, vhi, vlo,
                                                     mxp, rlp, w0, w1);
    k_final    <<<dim3(64, NB),    256, 0, stream>>>(x, w0, w1, gate, Amat, gm,
                                                     (float*)d_out);
}

// Round 5
// 503.951 us; speedup vs baseline: 1.1776x; 1.0582x over previous
//
#include <hip/hip_runtime.h>
#include <math.h>

#define NB 4
#define NC 256
#define NHW 4096
#define NC8 32
#define NC2 128

typedef unsigned short u16;
typedef __attribute__((ext_vector_type(8))) short s8v;   // 8 x bf16 (MFMA A/B frag)
typedef __attribute__((ext_vector_type(4))) short s4v;   // 4 x bf16
typedef __attribute__((ext_vector_type(4))) float f4v;   // 4 x f32  (MFMA C/D frag)

__device__ __forceinline__ u16 f2bf(float x) {
    unsigned int u = __builtin_bit_cast(unsigned int, x);
    u += 0x7FFFu + ((u >> 16) & 1u);          // RNE
    return (u16)(u >> 16);
}
__device__ __forceinline__ float bf2f(u16 h) {
    unsigned int u = ((unsigned int)h) << 16;
    return __builtin_bit_cast(float, u);
}
__device__ __forceinline__ s8v ld_sp(const u16* p) {   // 8B-aligned 16B LDS read (split)
    s4v a = *(const s4v*)p;
    s4v b = *(const s4v*)(p + 4);
    return __builtin_shufflevector(a, b, 0, 1, 2, 3, 4, 5, 6, 7);
}

#define MFMA16(a, b, c) __builtin_amdgcn_mfma_f32_16x16x32_bf16((a), (b), (c), 0, 0, 0)

// ---------------------------------------------------------------------------
// K1: conv3x3 partials. grid (16 co-groups of 4, 4 ci-chunks of 64, B).
// ---------------------------------------------------------------------------
__global__ __launch_bounds__(256) void k_conv_qk(
    const float* __restrict__ x,
    const float* __restrict__ qw, const float* __restrict__ kw,
    float* __restrict__ part)
{
    __shared__ float plane[2][64 * 65];
    const int cog = blockIdx.x;
    const int cic = blockIdx.y;
    const int b   = blockIdx.z;
    const int t   = threadIdx.x;
    const int co0 = cog * 4;
    const bool isq = co0 < NC8;
    const int oc0 = isq ? co0 : co0 - NC8;
    const float* wsel = isq ? qw : kw;
    const int ci0 = cic * 64;
    const int r  = t >> 2;
    const int c0 = (t & 3) * 16;
    float acc[4][16];
#pragma unroll
    for (int j = 0; j < 4; ++j)
#pragma unroll
        for (int q = 0; q < 16; ++q) acc[j][q] = 0.f;

    const float* xb = x + (size_t)b * NC * NHW;
    float4 pf[4];
    {
        const float4* src = (const float4*)(xb + (size_t)ci0 * NHW);
#pragma unroll
        for (int u = 0; u < 4; ++u) pf[u] = src[t + 256 * u];
    }
    for (int ci = ci0; ci < ci0 + 64; ++ci) {
        const int cur = ci & 1;
#pragma unroll
        for (int u = 0; u < 4; ++u) {
            int g  = (t + 256 * u) << 2;
            int rr = g >> 6, cc = g & 63;
            float* p = &plane[cur][rr * 65 + cc];
            p[0] = pf[u].x; p[1] = pf[u].y; p[2] = pf[u].z; p[3] = pf[u].w;
        }
        __syncthreads();
        if (ci + 1 < ci0 + 64) {
            const float4* src = (const float4*)(xb + (size_t)(ci + 1) * NHW);
#pragma unroll
            for (int u = 0; u < 4; ++u) pf[u] = src[t + 256 * u];
        }
        float w9[4][9];
#pragma unroll
        for (int j = 0; j < 4; ++j)
#pragma unroll
            for (int u = 0; u < 9; ++u)
                w9[j][u] = wsel[((size_t)(oc0 + j) * NC + ci) * 9 + u];
#pragma unroll
        for (int dy = 0; dy < 3; ++dy) {
            int rr = r + dy - 1;
            if (rr >= 0 && rr <= 63) {
                const float* row = &plane[cur][rr * 65];
                float tv[18];
#pragma unroll
                for (int jj = 0; jj < 18; ++jj) {
                    int cc = c0 + jj - 1;
                    tv[jj] = (cc >= 0 && cc < 64) ? row[cc] : 0.f;
                }
#pragma unroll
                for (int j = 0; j < 4; ++j) {
                    float wa = w9[j][dy * 3 + 0], wb = w9[j][dy * 3 + 1], wc = w9[j][dy * 3 + 2];
#pragma unroll
                    for (int q = 0; q < 16; ++q)
                        acc[j][q] += wa * tv[q] + wb * tv[q + 1] + wc * tv[q + 2];
                }
            }
        }
        __syncthreads();
    }
    float* pp = part + (((size_t)(cic * 4 + b) * 64 + co0) * NHW) + r * 64 + c0;
#pragma unroll
    for (int j = 0; j < 4; ++j)
#pragma unroll
        for (int q4 = 0; q4 < 4; ++q4) {
            float4 o;
            o.x = acc[j][q4 * 4 + 0]; o.y = acc[j][q4 * 4 + 1];
            o.z = acc[j][q4 * 4 + 2]; o.w = acc[j][q4 * 4 + 3];
            *(float4*)(pp + (size_t)j * NHW + q4 * 4) = o;
        }
}

// ---------------------------------------------------------------------------
// K1b: sum partials + bias + bn + relu -> q/k bf16 hi/lo, [b][pixel][32ch].
// ---------------------------------------------------------------------------
__global__ __launch_bounds__(256) void k_qk_finish(
    const float* __restrict__ part,
    const float* __restrict__ qb, const float* __restrict__ qbs, const float* __restrict__ qbb,
    const float* __restrict__ qbm, const float* __restrict__ qbv,
    const float* __restrict__ kb, const float* __restrict__ kbs, const float* __restrict__ kbb,
    const float* __restrict__ kbm, const float* __restrict__ kbv,
    u16* __restrict__ qh, u16* __restrict__ ql,
    u16* __restrict__ kh, u16* __restrict__ kl)
{
    const int t = threadIdx.x;
    const int b = blockIdx.y;
    const int n = blockIdx.x * 64 + (t & 63);
    const int coq = t >> 6;
    const int cb2 = coq * 16;
    float s[16];
#pragma unroll
    for (int j = 0; j < 16; ++j) s[j] = 0.f;
#pragma unroll
    for (int cic = 0; cic < 4; ++cic)
#pragma unroll
        for (int j = 0; j < 16; ++j)
            s[j] += part[(((size_t)(cic * 4 + b)) * 64 + cb2 + j) * NHW + n];
    const bool isq = coq < 2;
    u16 hi[16], lo[16];
#pragma unroll
    for (int j = 0; j < 16; ++j) {
        int oc = (coq & 1) * 16 + j;
        float cbv = isq ? qb[oc]  : kb[oc];
        float sv  = isq ? qbs[oc] : kbs[oc];
        float bbv = isq ? qbb[oc] : kbb[oc];
        float mv  = isq ? qbm[oc] : kbm[oc];
        float vv  = isq ? qbv[oc] : kbv[oc];
        float inv = rsqrtf(vv + 1e-5f);
        float scale = inv * sv;
        float shift = (cbv - mv) * scale + bbv;
        float y = fmaxf(s[j] * scale + shift, 0.f);
        hi[j] = f2bf(y);
        lo[j] = f2bf(y - bf2f(hi[j]));
    }
    u16* dh = isq ? qh : kh;
    u16* dl = isq ? ql : kl;
    size_t base = ((size_t)b * NHW + n) * 32 + (coq & 1) * 16;
    uint4 ph0, ph1, pl0, pl1;
    ph0.x = (unsigned)hi[0]  | ((unsigned)hi[1]  << 16);
    ph0.y = (unsigned)hi[2]  | ((unsigned)hi[3]  << 16);
    ph0.z = (unsigned)hi[4]  | ((unsigned)hi[5]  << 16);
    ph0.w = (unsigned)hi[6]  | ((unsigned)hi[7]  << 16);
    ph1.x = (unsigned)hi[8]  | ((unsigned)hi[9]  << 16);
    ph1.y = (unsigned)hi[10] | ((unsigned)hi[11] << 16);
    ph1.z = (unsigned)hi[12] | ((unsigned)hi[13] << 16);
    ph1.w = (unsigned)hi[14] | ((unsigned)hi[15] << 16);
    pl0.x = (unsigned)lo[0]  | ((unsigned)lo[1]  << 16);
    pl0.y = (unsigned)lo[2]  | ((unsigned)lo[3]  << 16);
    pl0.z = (unsigned)lo[4]  | ((unsigned)lo[5]  << 16);
    pl0.w = (unsigned)lo[6]  | ((unsigned)lo[7]  << 16);
    pl1.x = (unsigned)lo[8]  | ((unsigned)lo[9]  << 16);
    pl1.y = (unsigned)lo[10] | ((unsigned)lo[11] << 16);
    pl1.z = (unsigned)lo[12] | ((unsigned)lo[13] << 16);
    pl1.w = (unsigned)lo[14] | ((unsigned)lo[15] << 16);
    *(uint4*)&dh[base]     = ph0;
    *(uint4*)&dh[base + 8] = ph1;
    *(uint4*)&dl[base]     = pl0;
    *(uint4*)&dl[base + 8] = pl1;
}

// ---------------------------------------------------------------------------
// K2: dual 1x1 conv: v2T fp32 + v bf16 hi/lo [b][o][n].
// ---------------------------------------------------------------------------
__global__ __launch_bounds__(256) void k_gemm_vv2(
    const float* __restrict__ x,
    const float* __restrict__ vw, const float* __restrict__ vb,
    const float* __restrict__ sw, const float* __restrict__ sb,
    float* __restrict__ v2T, u16* __restrict__ vhi, u16* __restrict__ vlo)
{
    __shared__ float Ax[16 * 68];
    __shared__ float Bw1[16 * 68];
    __shared__ float Bw2[16 * 68];
    const int t  = threadIdx.x;
    const int n0 = blockIdx.x * 64;
    const int o0 = blockIdx.y * 64;
    const int b  = blockIdx.z;
    const int ni = t & 15, oi = t >> 4;
    float a1[4][4], a2[4][4];
#pragma unroll
    for (int i = 0; i < 4; ++i)
#pragma unroll
        for (int j = 0; j < 4; ++j) { a1[i][j] = 0.f; a2[i][j] = 0.f; }

    const int sk  = t >> 4;
    const int sf  = t & 15;
    const int so  = t & 63;
    const int skq = t >> 6;
    const float* xb = x + ((size_t)b * NC) * NHW + n0;

    float4 ax = *(const float4*)(xb + (size_t)sk * NHW + sf * 4);
    float4 f1 = *(const float4*)(vw + (size_t)(o0 + so) * NC + skq * 4);
    float4 f2 = *(const float4*)(sw + (size_t)(o0 + so) * NC + skq * 4);

    for (int c0 = 0; c0 < NC; c0 += 16) {
        *(float4*)&Ax[sk * 68 + sf * 4] = ax;
        Bw1[(skq * 4 + 0) * 68 + so] = f1.x;
        Bw1[(skq * 4 + 1) * 68 + so] = f1.y;
        Bw1[(skq * 4 + 2) * 68 + so] = f1.z;
        Bw1[(skq * 4 + 3) * 68 + so] = f1.w;
        Bw2[(skq * 4 + 0) * 68 + so] = f2.x;
        Bw2[(skq * 4 + 1) * 68 + so] = f2.y;
        Bw2[(skq * 4 + 2) * 68 + so] = f2.z;
        Bw2[(skq * 4 + 3) * 68 + so] = f2.w;
        __syncthreads();
        if (c0 + 16 < NC) {
            ax = *(const float4*)(xb + (size_t)(c0 + 16 + sk) * NHW + sf * 4);
            f1 = *(const float4*)(vw + (size_t)(o0 + so) * NC + c0 + 16 + skq * 4);
            f2 = *(const float4*)(sw + (size_t)(o0 + so) * NC + c0 + 16 + skq * 4);
        }
#pragma unroll
        for (int k = 0; k < 16; ++k) {
            float4 af = *(const float4*)&Ax[k * 68 + ni * 4];
            float4 g1 = *(const float4*)&Bw1[k * 68 + oi * 4];
            float4 g2 = *(const float4*)&Bw2[k * 68 + oi * 4];
            const float* ap = (const float*)&af;
            const float* p1 = (const float*)&g1;
            const float* p2 = (const float*)&g2;
#pragma unroll
            for (int i = 0; i < 4; ++i)
#pragma unroll
                for (int j = 0; j < 4; ++j) {
                    a1[i][j] += ap[i] * p1[j];
                    a2[i][j] += ap[i] * p2[j];
                }
        }
        __syncthreads();
    }
    float vb4[4], sb4[4];
#pragma unroll
    for (int j = 0; j < 4; ++j) { vb4[j] = vb[o0 + oi * 4 + j]; sb4[j] = sb[o0 + oi * 4 + j]; }
#pragma unroll
    for (int i = 0; i < 4; ++i) {
        size_t idx = ((size_t)b * NHW + n0 + ni * 4 + i) * NC + o0 + oi * 4;
        float4 o2v;
        o2v.x = a2[i][0] + sb4[0]; o2v.y = a2[i][1] + sb4[1];
        o2v.z = a2[i][2] + sb4[2]; o2v.w = a2[i][3] + sb4[3];
        *(float4*)&v2T[idx] = o2v;
    }
#pragma unroll
    for (int j = 0; j < 4; ++j) {
        u16 h[4], l[4];
#pragma unroll
        for (int i = 0; i < 4; ++i) {
            float y = a1[i][j] + vb4[j];
            h[i] = f2bf(y);
            l[i] = f2bf(y - bf2f(h[i]));
        }
        size_t vi = ((size_t)b * NC + o0 + oi * 4 + j) * NHW + n0 + ni * 4;
        uint2 uh, ul;
        uh.x = (unsigned)h[0] | ((unsigned)h[1] << 16);
        uh.y = (unsigned)h[2] | ((unsigned)h[3] << 16);
        ul.x = (unsigned)l[0] | ((unsigned)l[1] << 16);
        ul.y = (unsigned)l[2] | ((unsigned)l[3] << 16);
        *(uint2*)&vhi[vi] = uh;
        *(uint2*)&vlo[vi] = ul;
    }
}

// ---------------------------------------------------------------------------
// K3: channel max/mean of v2T rows -> smo[b,{max,mean},n]
// ---------------------------------------------------------------------------
__global__ __launch_bounds__(256) void k_reduce_v2(const float* __restrict__ v2T,
                                                   float* __restrict__ smo)
{
    const int t = threadIdx.x;
    const int lane = t & 63, wv = t >> 6;
    const int row = blockIdx.x * 4 + wv;
    float4 f = ((const float4*)(v2T + (size_t)row * NC))[lane];
    float mx = fmaxf(fmaxf(f.x, f.y), fmaxf(f.z, f.w));
    float sm = f.x + f.y + f.z + f.w;
#pragma unroll
    for (int off = 32; off; off >>= 1) {
        mx = fmaxf(mx, __shfl_down(mx, off));
        sm += __shfl_down(sm, off);
    }
    if (lane == 0) {
        int b = row >> 12, n = row & 4095;
        smo[((size_t)b * 2 + 0) * NHW + n] = mx;
        smo[((size_t)b * 2 + 1) * NHW + n] = sm * (1.f / NC);
    }
}

// ---------------------------------------------------------------------------
// K4: conv3x3(2ch->1) + bn + row softmax -> Amat[b,w,k]
// ---------------------------------------------------------------------------
__global__ __launch_bounds__(256) void k_spatial(
    const float* __restrict__ smo, const float* __restrict__ scw,
    const float* __restrict__ scb, const float* __restrict__ sbs,
    const float* __restrict__ sbb2, const float* __restrict__ sbm,
    const float* __restrict__ sbv, float* __restrict__ Amat)
{
    __shared__ float ch[2][64 * 68];
    __shared__ float lg[64 * 68];
    const int t = threadIdx.x;
    const int b = blockIdx.x;
#pragma unroll
    for (int u = 0; u < 8; ++u) {
        int g  = t + 256 * u;
        int c  = g >> 10, gi = g & 1023;
        int row = gi >> 4, col4 = (gi & 15) * 4;
        float4 f = ((const float4*)(smo + ((size_t)b * 2 + c) * NHW))[gi];
        *(float4*)&ch[c][row * 68 + col4] = f;
    }
    __syncthreads();
    float w9[2][9];
#pragma unroll
    for (int ic = 0; ic < 2; ++ic)
#pragma unroll
        for (int j = 0; j < 9; ++j) w9[ic][j] = scw[ic * 9 + j];
    float A0, Bsh;
    {
        float inv = rsqrtf(sbv[0] + 1e-5f);
        A0  = inv * sbs[0];
        Bsh = (scb[0] - sbm[0]) * A0 + sbb2[0];
    }
#pragma unroll
    for (int u = 0; u < 16; ++u) {
        int px = t + 256 * u;
        int h = px >> 6, w = px & 63;
        float acc = 0.f;
#pragma unroll
        for (int ic = 0; ic < 2; ++ic)
#pragma unroll
            for (int dy = 0; dy < 3; ++dy) {
                int rr = h + dy - 1;
                if (rr < 0 || rr > 63) continue;
#pragma unroll
                for (int dx = 0; dx < 3; ++dx) {
                    int cc = w + dx - 1;
                    if (cc < 0 || cc > 63) continue;
                    acc += w9[ic][dy * 3 + dx] * ch[ic][rr * 68 + cc];
                }
            }
        lg[h * 68 + w] = acc * A0 + Bsh;
    }
    __syncthreads();
    if (t < 64) {
        float M = -INFINITY;
        for (int k2 = 0; k2 < 64; ++k2) M = fmaxf(M, lg[t * 68 + k2]);
        float L = 0.f;
        for (int k2 = 0; k2 < 64; ++k2) L += __expf(lg[t * 68 + k2] - M);
        float rli = 1.f / L;
        for (int k2 = 0; k2 < 64; ++k2)
            Amat[(size_t)b * NHW + t * 64 + k2] = __expf(lg[t * 68 + k2] - M) * rli;
    }
}

// ---------------------------------------------------------------------------
// K5: per-(b,c) spatial mean & max of x
// ---------------------------------------------------------------------------
__global__ __launch_bounds__(256) void k_xstats(const float* __restrict__ x,
                                                float* __restrict__ smean,
                                                float* __restrict__ smax)
{
    const int t = threadIdx.x;
    const int c = blockIdx.x, b = blockIdx.y;
    const float* row = x + ((size_t)b * NC + c) * NHW;
    float s = 0.f, m = -INFINITY;
#pragma unroll
    for (int u = 0; u < 4; ++u) {
        float4 f = ((const float4*)row)[t + 256 * u];
        s += f.x + f.y + f.z + f.w;
        m = fmaxf(m, fmaxf(fmaxf(f.x, f.y), fmaxf(f.z, f.w)));
    }
    __shared__ float red[8];
    const int lane = t & 63, wv = t >> 6;
#pragma unroll
    for (int off = 32; off; off >>= 1) {
        s += __shfl_down(s, off);
        m = fmaxf(m, __shfl_down(m, off));
    }
    if (lane == 0) { red[wv] = s; red[4 + wv] = m; }
    __syncthreads();
    if (t == 0) {
        float S = red[0] + red[1] + red[2] + red[3];
        float M = fmaxf(fmaxf(red[4], red[5]), fmaxf(red[6], red[7]));
        smean[b * NC + c] = S * (1.f / NHW);
        smax[b * NC + c]  = M;
    }
}

// ---------------------------------------------------------------------------
// K6: channel gate
// ---------------------------------------------------------------------------
__global__ __launch_bounds__(256) void k_gate(
    const float* __restrict__ smean, const float* __restrict__ smax,
    const float* __restrict__ w1, const float* __restrict__ b1,
    const float* __restrict__ w2, const float* __restrict__ b2,
    float* __restrict__ gate)
{
    __shared__ float smL[256], sxL[256], hL[256];
    const int t = threadIdx.x;
    const int b = blockIdx.x;
    smL[t] = smean[b * NC + t];
    sxL[t] = smax[b * NC + t];
    __syncthreads();
    {
        const int j = t & 127;
        const float* in = (t < 128) ? smL : sxL;
        const float* wr = w1 + (size_t)j * NC;
        float acc = b1[j];
        for (int c = 0; c < NC; c += 4) {
            float4 f = *(const float4*)(wr + c);
            acc += f.x * in[c] + f.y * in[c + 1] + f.z * in[c + 2] + f.w * in[c + 3];
        }
        hL[t] = fmaxf(acc, 0.f);
    }
    __syncthreads();
    {
        const float* wr = w2 + (size_t)t * NC2;
        float acc = 2.f * b2[t];
        for (int j = 0; j < NC2; j += 4) {
            float4 f = *(const float4*)(wr + j);
            acc += f.x * (hL[j]     + hL[128 + j])
                 + f.y * (hL[j + 1] + hL[129 + j])
                 + f.z * (hL[j + 2] + hL[130 + j])
                 + f.w * (hL[j + 3] + hL[131 + j]);
        }
        gate[b * NC + t] = 1.f / (1.f + __expf(-acc));
    }
}

// ---------------------------------------------------------------------------
// K7: softmax row stats via bf16-split MFMA (swapped: S^T = K^T Q).
// ---------------------------------------------------------------------------
__global__ __launch_bounds__(64) void k_softstats(
    const u16* __restrict__ qh, const u16* __restrict__ ql,
    const u16* __restrict__ kh, const u16* __restrict__ kl,
    float* __restrict__ mx, float* __restrict__ rl)
{
    const int t  = threadIdx.x;
    const int li = t & 15, g = t >> 4;
    const int n0 = blockIdx.x * 16;
    const int b  = blockIdx.y;
    const size_t qoff = ((size_t)b * NHW + n0 + li) * 32 + g * 8;
    const s8v qfh = *(const s8v*)&qh[qoff];
    const s8v qfl = *(const s8v*)&ql[qoff];
    const size_t kb0 = ((size_t)b * NHW + li) * 32 + g * 8;
    s8v ka0 = *(const s8v*)&kh[kb0];
    s8v ka1 = *(const s8v*)&kh[kb0 + 512];
    s8v la0 = *(const s8v*)&kl[kb0];
    s8v la1 = *(const s8v*)&kl[kb0 + 512];
    float mrun = -INFINITY, lrun = 0.f;
    for (int it = 0; it < 128; ++it) {
        f4v c0 = {0.f, 0.f, 0.f, 0.f}, c1 = {0.f, 0.f, 0.f, 0.f};
        c0 = MFMA16(ka0, qfh, c0); c0 = MFMA16(ka0, qfl, c0); c0 = MFMA16(la0, qfh, c0);
        c1 = MFMA16(ka1, qfh, c1); c1 = MFMA16(ka1, qfl, c1); c1 = MFMA16(la1, qfh, c1);
        if (it + 1 < 128) {
            size_t o = kb0 + (size_t)(it + 1) * 1024;
            ka0 = *(const s8v*)&kh[o];
            ka1 = *(const s8v*)&kh[o + 512];
            la0 = *(const s8v*)&kl[o];
            la1 = *(const s8v*)&kl[o + 512];
        }
        float tmax = fmaxf(fmaxf(fmaxf(c0[0], c0[1]), fmaxf(c0[2], c0[3])),
                           fmaxf(fmaxf(c1[0], c1[1]), fmaxf(c1[2], c1[3])));
        tmax = fmaxf(tmax, __shfl_xor(tmax, 16));
        tmax = fmaxf(tmax, __shfl_xor(tmax, 32));
        float nm = fmaxf(mrun, tmax);
        float ls = 0.f;
#pragma unroll
        for (int r = 0; r < 4; ++r) ls += __expf(c0[r] - nm);
#pragma unroll
        for (int r = 0; r < 4; ++r) ls += __expf(c1[r] - nm);
        ls += __shfl_xor(ls, 16);
        ls += __shfl_xor(ls, 32);
        lrun = lrun * __expf(mrun - nm) + ls;
        mrun = nm;
    }
    if (g == 0) {
        mx[(size_t)b * NHW + n0 + li] = mrun;
        rl[(size_t)b * NHW + n0 + li] = 1.f / lrun;
    }
}

// ---------------------------------------------------------------------------
// K8 v3: flash pass B. 512 threads (8 waves), 16 waves/CU.
// m split in 4 quarters (mh), 32 iters of 32m. Waves 0-3: QK (ng=wv) +
// softmax + Sp produce; waves 4-7: K LDS-staging (2-deep reg pipeline).
// All 8 waves: PV over a 32-wide c-slice, V B-frags direct from global/L2.
// RAW barrier (lgkmcnt only) -- global prefetches stay in flight across it.
// Outputs bf16 partials w[mh][b][n][c].
// ---------------------------------------------------------------------------
__global__ __launch_bounds__(512, 4) void k_flash(
    const u16* __restrict__ qh, const u16* __restrict__ ql,
    const u16* __restrict__ kh, const u16* __restrict__ kl,
    const u16* __restrict__ vhi, const u16* __restrict__ vlo,
    const float* __restrict__ mx, const float* __restrict__ rl,
    u16* __restrict__ w)
{
    __shared__ __align__(16) u16 Sk[2][2][32 * 40];   // [buf][hi/lo][m' x 40]
    __shared__ __align__(16) u16 Sp[2][4][16 * 36];   // [buf][ng][n-row x 36]
    const int t = threadIdx.x;
    const int bid = blockIdx.x;
    const int v   = (bid & 7) * 128 + (bid >> 3);     // XCD swizzle (1024 = 8*128)
    const int n0  = (v & 63) * 64;
    const int mh  = (v >> 6) & 3;
    const int b   = v >> 8;
    const int mbase = mh * 1024;
    const int li = t & 15, g = (t >> 4) & 3, wv = t >> 6;
    const bool qkrole = wv < 4;

    // ---- per-role persistent state ----
    s8v qfh = {0,0,0,0,0,0,0,0}, qfl = {0,0,0,0,0,0,0,0};
    float mxv = 0.f, rlv = 0.f;
    if (qkrole) {
        const size_t qoff = ((size_t)b * NHW + n0 + wv * 16 + li) * 32 + g * 8;
        qfh = *(const s8v*)&qh[qoff];
        qfl = *(const s8v*)&ql[qoff];
        mxv = mx[(size_t)b * NHW + n0 + wv * 16 + li];
        rlv = rl[(size_t)b * NHW + n0 + wv * 16 + li];
    }
    // K staging params (waves 4-7)
    const int tid2 = t - 256;
    const int sel  = (tid2 >> 7) & 1;
    const int sidx = tid2 & 127;
    const int smp  = sidx >> 2;
    const int sc8  = (sidx & 3) * 8;
    const u16* ksrc = sel ? kl : kh;
    const size_t kgbase = ((size_t)b * NHW + mbase + smp) * 32 + sc8;
    s8v kreg = {0,0,0,0,0,0,0,0};
    if (!qkrole) {
        kreg = *(const s8v*)&ksrc[kgbase];               // K(0)
        *(s8v*)&Sk[0][sel][smp * 40 + sc8] = kreg;
        kreg = *(const s8v*)&ksrc[kgbase + 1024];        // K(1) held in reg
    }
    // V B-frag prefetch (all waves): c-slice = wv*32 .. +31 (2 ct of 16)
    const size_t vb0 = ((size_t)b * NC + wv * 32 + li) * NHW + mbase + g * 8;
    s8v vfh[2], vfl[2];
#pragma unroll
    for (int ct = 0; ct < 2; ++ct) {
        vfh[ct] = *(const s8v*)&vhi[vb0 + (size_t)ct * 16 * NHW];
        vfl[ct] = *(const s8v*)&vlo[vb0 + (size_t)ct * 16 * NHW];
    }
    f4v acc[4][2];
#pragma unroll
    for (int i = 0; i < 4; ++i)
#pragma unroll
        for (int j = 0; j < 2; ++j) { f4v z = {0.f, 0.f, 0.f, 0.f}; acc[i][j] = z; }

    __syncthreads();                                     // prologue (Sk[0] ready)

    for (int it = 0; it < 32; ++it) {
        if (qkrole) {
            // ---- K A-frags from LDS; S^T = K^T Q for ng=wv ----
            const u16* skh = &Sk[it & 1][0][0];
            const u16* skl = &Sk[it & 1][1][0];
            s8v ka0 = *(const s8v*)&skh[li * 40 + g * 8];
            s8v ka1 = *(const s8v*)&skh[(16 + li) * 40 + g * 8];
            s8v la0 = *(const s8v*)&skl[li * 40 + g * 8];
            s8v la1 = *(const s8v*)&skl[(16 + li) * 40 + g * 8];
            f4v c0 = {0.f, 0.f, 0.f, 0.f}, c1 = {0.f, 0.f, 0.f, 0.f};
            c0 = MFMA16(ka0, qfh, c0); c0 = MFMA16(ka0, qfl, c0); c0 = MFMA16(la0, qfh, c0);
            c1 = MFMA16(ka1, qfh, c1); c1 = MFMA16(ka1, qfl, c1); c1 = MFMA16(la1, qfh, c1);
            // ---- P = exp(S - mx) * rl (bf16 hi) -> Sp ----
            u16 h0[4], h1[4];
#pragma unroll
            for (int r = 0; r < 4; ++r) {
                h0[r] = f2bf(__expf(c0[r] - mxv) * rlv);
                h1[r] = f2bf(__expf(c1[r] - mxv) * rlv);
            }
            u16* sp = &Sp[it & 1][wv][0];
            uint2 uw0, uw1;
            uw0.x = (unsigned)h0[0] | ((unsigned)h0[1] << 16);
            uw0.y = (unsigned)h0[2] | ((unsigned)h0[3] << 16);
            uw1.x = (unsigned)h1[0] | ((unsigned)h1[1] << 16);
            uw1.y = (unsigned)h1[2] | ((unsigned)h1[3] << 16);
            *(uint2*)&sp[li * 36 + g * 4]      = uw0;    // m = g*4..+3
            *(uint2*)&sp[li * 36 + 16 + g * 4] = uw1;    // m = 16+g*4..+3
        } else {
            // ---- stage K(it+1) into LDS; issue K(it+2) ----
            *(s8v*)&Sk[(it + 1) & 1][sel][smp * 40 + sc8] = kreg;
            kreg = *(const s8v*)&ksrc[kgbase + (size_t)(it + 2) * 1024];  // tail over-read in ws
        }
        asm volatile("s_waitcnt lgkmcnt(0)" ::: "memory");
        __builtin_amdgcn_s_barrier();                    // raw: vmcnt stays in flight
        asm volatile("" ::: "memory");
        // ---- P A-frags (all 4 ngs), PV over this wave's c-slice ----
        s8v pa[4];
#pragma unroll
        for (int ng = 0; ng < 4; ++ng)
            pa[ng] = ld_sp(&Sp[it & 1][ng][li * 36 + g * 8]);
#pragma unroll
        for (int ng = 0; ng < 4; ++ng) {
            acc[ng][0] = MFMA16(pa[ng], vfh[0], acc[ng][0]);
            acc[ng][0] = MFMA16(pa[ng], vfl[0], acc[ng][0]);
            acc[ng][1] = MFMA16(pa[ng], vfh[1], acc[ng][1]);
            acc[ng][1] = MFMA16(pa[ng], vfl[1], acc[ng][1]);
        }
        {   // V prefetch it+1 (tail over-read stays inside workspace)
            size_t o = vb0 + (size_t)(it + 1) * 32;
#pragma unroll
            for (int ct = 0; ct < 2; ++ct) {
                vfh[ct] = *(const s8v*)&vhi[o + (size_t)ct * 16 * NHW];
                vfl[ct] = *(const s8v*)&vlo[o + (size_t)ct * 16 * NHW];
            }
        }
    }
    // ---- epilogue: bf16 partial store ----
    u16* wout = w + (size_t)mh * 4194304;
#pragma unroll
    for (int ng = 0; ng < 4; ++ng)
#pragma unroll
        for (int ct = 0; ct < 2; ++ct)
#pragma unroll
            for (int r = 0; r < 4; ++r)
                wout[((size_t)b * NHW + n0 + ng * 16 + g * 4 + r) * NC
                     + wv * 32 + ct * 16 + li] = f2bf(acc[ng][ct][r]);
}

// ---------------------------------------------------------------------------
// K9: out = gamma*sum(w_mh) + x*(1+gate) + x @ A  -- LDS-tiled mini-GEMM
// ---------------------------------------------------------------------------
__global__ __launch_bounds__(256) void k_final(
    const float* __restrict__ x, const u16* __restrict__ wp,
    const float* __restrict__ gate,
    const float* __restrict__ Amat, const float* __restrict__ gamma,
    float* __restrict__ out)
{
    __shared__ float As[64 * 65];
    __shared__ float xs[64 * 65];
    const int t = threadIdx.x;
    const int h = blockIdx.x, b = blockIdx.y;
    const float g0 = gamma[0];
    const int kq = t >> 4;
    const int cq = t & 15;
#pragma unroll
    for (int u = 0; u < 4; ++u) {
        int gidx = t + 256 * u;
        int w = gidx >> 4, k4 = (gidx & 15) * 4;
        float4 f = ((const float4*)(Amat + (size_t)b * NHW))[gidx];
        *(float4*)&As[w * 65 + k4] = f;
    }
    for (int ch = 0; ch < 4; ++ch) {
        __syncthreads();
#pragma unroll
        for (int u = 0; u < 4; ++u) {
            int gidx = t + 256 * u;
            int c = gidx >> 4, w4 = (gidx & 15) * 4;
            float4 f = *(const float4*)(x + ((size_t)(b * NC) + ch * 64 + c) * NHW + h * 64 + w4);
            xs[(w4 + 0) * 65 + c] = f.x;
            xs[(w4 + 1) * 65 + c] = f.y;
            xs[(w4 + 2) * 65 + c] = f.z;
            xs[(w4 + 3) * 65 + c] = f.w;
        }
        __syncthreads();
        float acc[4][4];
#pragma unroll
        for (int i = 0; i < 4; ++i)
#pragma unroll
            for (int j = 0; j < 4; ++j) acc[i][j] = 0.f;
        for (int w = 0; w < 64; ++w) {
            float4 av = *(const float4*)&As[w * 65 + kq * 4];
            float4 xv = *(const float4*)&xs[w * 65 + cq * 4];
            const float* ap = (const float*)&av;
            const float* xp = (const float*)&xv;
#pragma unroll
            for (int i = 0; i < 4; ++i)
#pragma unroll
                for (int j = 0; j < 4; ++j)
                    acc[i][j] += xp[i] * ap[j];
        }
        float gt1[4];
#pragma unroll
        for (int i = 0; i < 4; ++i) gt1[i] = 1.f + gate[b * NC + ch * 64 + cq * 4 + i];
#pragma unroll
        for (int j = 0; j < 4; ++j) {
            const int k = kq * 4 + j;
            const int n = h * 64 + k;
            size_t wb = ((size_t)b * NHW + n) * NC + ch * 64 + cq * 4;
            float ws4[4] = {0.f, 0.f, 0.f, 0.f};
#pragma unroll
            for (int m = 0; m < 4; ++m) {
                uint2 uw = *(const uint2*)&wp[(size_t)m * 4194304 + wb];
                ws4[0] += bf2f((u16)(uw.x & 0xffff));
                ws4[1] += bf2f((u16)(uw.x >> 16));
                ws4[2] += bf2f((u16)(uw.y & 0xffff));
                ws4[3] += bf2f((u16)(uw.y >> 16));
            }
#pragma unroll
            for (int i = 0; i < 4; ++i) {
                const int c = ch * 64 + cq * 4 + i;
                const float xv = xs[k * 65 + cq * 4 + i];
                out[((size_t)(b * NC + c)) * NHW + n] = g0 * ws4[i] + xv * gt1[i] + acc[i][j];
            }
        }
    }
}

// ---------------------------------------------------------------------------
extern "C" void kernel_launch(void* const* d_in, const int* in_sizes, int n_in,
                              void* d_out, int out_size, void* d_ws, size_t ws_size,
                              hipStream_t stream)
{
    const float* x    = (const float*)d_in[0];
    const float* qw   = (const float*)d_in[1];
    const float* qb   = (const float*)d_in[2];
    const float* qbs  = (const float*)d_in[3];
    const float* qbb  = (const float*)d_in[4];
    const float* qbm  = (const float*)d_in[5];
    const float* qbv  = (const float*)d_in[6];
    const float* kw   = (const float*)d_in[7];
    const float* kb   = (const float*)d_in[8];
    const float* kbs  = (const float*)d_in[9];
    const float* kbb  = (const float*)d_in[10];
    const float* kbm  = (const float*)d_in[11];
    const float* kbv  = (const float*)d_in[12];
    const float* vw   = (const float*)d_in[13];
    const float* vb   = (const float*)d_in[14];
    const float* gm   = (const float*)d_in[15];
    const float* cw1  = (const float*)d_in[16];
    const float* cb1  = (const float*)d_in[17];
    const float* cw2  = (const float*)d_in[18];
    const float* cb2  = (const float*)d_in[19];
    const float* svw  = (const float*)d_in[20];
    const float* svb  = (const float*)d_in[21];
    const float* scw  = (const float*)d_in[22];
    const float* scb  = (const float*)d_in[23];
    const float* sbs  = (const float*)d_in[24];
    const float* sbb  = (const float*)d_in[25];
    const float* sbm  = (const float*)d_in[26];
    const float* sbv  = (const float*)d_in[27];

    float* ws    = (float*)d_ws;
    float* part  = ws;                      // [0, 4194304) f     -> later w[0..1]
    float* v2T   = ws + 4194304;            // [4194304, 8388608) -> later w[2..3]
    u16*   wbf   = (u16*)ws;                // 4 x 4,194,304 u16 partials (aliases above)
    u16*   vhi   = (u16*)(ws + 8388608);    // 4,194,304 u16
    u16*   vlo   = (u16*)(ws + 10485760);
    u16*   qhB   = (u16*)(ws + 12582912);   //   524,288 u16 each
    u16*   qlB   = (u16*)(ws + 12845056);
    u16*   khB   = (u16*)(ws + 13107200);
    u16*   klB   = (u16*)(ws + 13369344);
    float* mxp   = ws + 13631488;
    float* rlp   = ws + 13647872;
    float* smean = ws + 13664256;
    float* smax  = ws + 13665280;
    float* gate  = ws + 13666304;
    float* smo   = ws + 13667328;
    float* Amat  = ws + 13700096;
    // total 13,716,480 floats ~= 54.9 MB

    k_conv_qk  <<<dim3(16, 4, NB), 256, 0, stream>>>(x, qw, kw, part);
    k_qk_finish<<<dim3(64, NB),    256, 0, stream>>>(part, qb, qbs, qbb, qbm, qbv,
                                                     kb, kbs, kbb, kbm, kbv,
                                                     qhB, qlB, khB, klB);
    k_gemm_vv2 <<<dim3(64, 4, NB), 256, 0, stream>>>(x, vw, vb, svw, svb, v2T, vhi, vlo);
    k_reduce_v2<<<dim3(4096),      256, 0, stream>>>(v2T, smo);
    k_spatial  <<<dim3(NB),        256, 0, stream>>>(smo, scw, scb, sbs, sbb, sbm, sbv, Amat);
    k_xstats   <<<dim3(NC, NB),    256, 0, stream>>>(x, smean, smax);
    k_gate     <<<dim3(NB),        256, 0, stream>>>(smean, smax, cw1, cb1, cw2, cb2, gate);
    k_softstats<<<dim3(256, NB),   64,  0, stream>>>(qhB, qlB, khB, klB, mxp, rlp);
    k_flash    <<<dim3(1024),      512, 0, stream>>>(qhB, qlB, khB, klB, vhi, vlo,
                                                     mxp, rlp, wbf);
    k_final    <<<dim3(64, NB),    256, 0, stream>>>(x, wbf, gate, Amat, gm,
                                                     (float*)d_out);
}